// Round 1
// baseline (3211.959 us; speedup 1.0000x reference)
//
#include <hip/hip_runtime.h>

// GIN forward: h = x@W_pre.T + b_pre
//              h = relu((h + scatter_sum(h[src]->dst)) @ W_first.T + b_first)
//              out = (h + scatter_sum(h[src]->dst)) @ W_out.T + b_out
// N=100000, E=1600000, IN=128, D=64.

// ---------------------------------------------------------------------------
// Node GEMM: out[N,64] = act((A [+ A2])[N,K] @ W[64,K]^T + bias)
// Tile: ROWS=16*RPT rows x 64 cols per block of 256 threads.
// Thread: RPT rows x 4 cols. W transposed in LDS -> per-k read is one
// conflict-free ds_read_b128 (16 lanes x 16B = 256B spanning all banks).
// x tile has odd row stride (K+1) so the 4 distinct row-broadcast reads per
// wave land in distinct banks (free 2-way at worst).
// ---------------------------------------------------------------------------
template <int K, int RPT>
__global__ __launch_bounds__(256) void gemm_nodes(
    const float* __restrict__ A, const float* __restrict__ A2,
    const float* __restrict__ W, const float* __restrict__ bias,
    float* __restrict__ out, int N, int relu)
{
    constexpr int ROWS = 16 * RPT;
    __shared__ float xs[ROWS][K + 1];
    __shared__ float wt[K * 64];

    const int tid = threadIdx.x;

    // Load W[64][K] transposed into wt[k][j] (coalesced global reads).
    for (int idx = tid; idx < 64 * K; idx += 256) {
        const int j = idx >> (K == 128 ? 7 : 6);
        const int k = idx & (K - 1);
        wt[k * 64 + j] = W[idx];
    }

    // Load x tile (optionally + A2) with float4 global loads.
    const int base = blockIdx.x * ROWS;
    constexpr int Q = K / 4;
    for (int i4 = tid; i4 < ROWS * Q; i4 += 256) {
        const int r = i4 / Q;
        const int q = i4 - r * Q;
        int row = base + r;
        if (row > N - 1) row = N - 1;   // clamp stays inside this block's rows
        float4 v = *(const float4*)(A + (size_t)row * K + q * 4);
        if (A2) {
            const float4 vb = *(const float4*)(A2 + (size_t)row * K + q * 4);
            v.x += vb.x; v.y += vb.y; v.z += vb.z; v.w += vb.w;
        }
        float* p = &xs[r][q * 4];
        p[0] = v.x; p[1] = v.y; p[2] = v.z; p[3] = v.w;
    }
    __syncthreads();

    const int cg = tid & 15;   // col group: cols 4*cg .. 4*cg+3
    const int rs = tid >> 4;   // row slot:  rows rs + 16*i

    float acc[RPT][4];
    const float4 bv = *(const float4*)(bias + 4 * cg);
#pragma unroll
    for (int i = 0; i < RPT; ++i) {
        acc[i][0] = bv.x; acc[i][1] = bv.y; acc[i][2] = bv.z; acc[i][3] = bv.w;
    }

#pragma unroll
    for (int k = 0; k < K; ++k) {
        const float4 w4 = *(const float4*)&wt[k * 64 + 4 * cg];
#pragma unroll
        for (int i = 0; i < RPT; ++i) {
            const float a = xs[rs + 16 * i][k];
            acc[i][0] += a * w4.x;
            acc[i][1] += a * w4.y;
            acc[i][2] += a * w4.z;
            acc[i][3] += a * w4.w;
        }
    }

#pragma unroll
    for (int i = 0; i < RPT; ++i) {
        const int row = base + rs + 16 * i;
        if (row < N) {
            float4 r4 = make_float4(acc[i][0], acc[i][1], acc[i][2], acc[i][3]);
            if (relu) {
                r4.x = fmaxf(r4.x, 0.f); r4.y = fmaxf(r4.y, 0.f);
                r4.z = fmaxf(r4.z, 0.f); r4.w = fmaxf(r4.w, 0.f);
            }
            *(float4*)(out + (size_t)row * 64 + 4 * cg) = r4;
        }
    }
}

// ---------------------------------------------------------------------------
// Edge scatter: agg[dst] += h[src], one edge handled by 16 threads (float4
// gather = coalesced 256B row read, 4 scalar f32 atomics per thread).
// ---------------------------------------------------------------------------
__global__ __launch_bounds__(256) void scatter_add(
    const float* __restrict__ h, const int* __restrict__ src,
    const int* __restrict__ dst, float* __restrict__ agg, int E)
{
    const int g = blockIdx.x * 256 + threadIdx.x;
    const int e = g >> 4;
    if (e >= E) return;
    const int q = (g & 15) * 4;
    const int s = src[e];
    const int d = dst[e];
    const float4 v = *(const float4*)(h + (size_t)s * 64 + q);
    float* p = agg + (size_t)d * 64 + q;
    atomicAdd(p + 0, v.x);
    atomicAdd(p + 1, v.y);
    atomicAdd(p + 2, v.z);
    atomicAdd(p + 3, v.w);
}

extern "C" void kernel_launch(void* const* d_in, const int* in_sizes, int n_in,
                              void* d_out, int out_size, void* d_ws, size_t ws_size,
                              hipStream_t stream)
{
    const float* x       = (const float*)d_in[0];
    const int*   ei      = (const int*)  d_in[1];
    const float* W_pre   = (const float*)d_in[2];
    const float* b_pre   = (const float*)d_in[3];
    const float* W_first = (const float*)d_in[4];
    const float* b_first = (const float*)d_in[5];
    const float* W_out   = (const float*)d_in[6];
    const float* b_out   = (const float*)d_in[7];

    const int N = in_sizes[0] / 128;
    const int E = in_sizes[1] / 2;
    const int* src = ei;
    const int* dst = ei + E;

    float* h   = (float*)d_ws;    // [N,64] hidden state (25.6 MB)
    float* agg = (float*)d_out;   // d_out doubles as the aggregation scratch
    float* out = (float*)d_out;

    const size_t feat_bytes = (size_t)N * 64 * sizeof(float);

    const int gemm_pre_grid  = (N + 31) / 64 * 2 + ((N % 32) ? 1 : 0); // = ceil(N/32)
    const int gemm_pre_blocks = (N + 31) / 32;
    const int gemm_conv_blocks = (N + 63) / 64;
    const int scat_blocks = (E * 16 + 255) / 256;
    (void)gemm_pre_grid;

    // 1. h = x @ W_pre.T + b_pre          (K=128, 32-row tiles)
    gemm_nodes<128, 2><<<gemm_pre_blocks, 256, 0, stream>>>(
        x, nullptr, W_pre, b_pre, h, N, 0);

    // 2. agg = scatter_sum(h[src] -> dst)
    hipMemsetAsync(agg, 0, feat_bytes, stream);
    scatter_add<<<scat_blocks, 256, 0, stream>>>(h, src, dst, agg, E);

    // 3. h = relu((h + agg) @ W_first.T + b_first)   (in-place on h: each
    //    block loads its own rows to LDS before writing them)
    gemm_nodes<64, 4><<<gemm_conv_blocks, 256, 0, stream>>>(
        h, agg, W_first, b_first, h, N, 1);

    // 4. agg = scatter_sum(h[src] -> dst)
    hipMemsetAsync(agg, 0, feat_bytes, stream);
    scatter_add<<<scat_blocks, 256, 0, stream>>>(h, src, dst, agg, E);

    // 5. out = (h + agg) @ W_out.T + b_out  (agg==d_out input, out==d_out:
    //    safe, blocks only read rows they themselves write)
    gemm_nodes<64, 4><<<gemm_conv_blocks, 256, 0, stream>>>(
        h, agg, W_out, b_out, out, N, 0);
}

// Round 3
// 810.622 us; speedup vs baseline: 3.9623x; 3.9623x over previous
//
#include <hip/hip_runtime.h>

// GIN forward: h = x@W_pre.T + b_pre
//              h = relu((h + seg_sum(h[src]->dst)) @ W_first.T + b_first)
//              out = (h + seg_sum(h[src]->dst)) @ W_out.T + b_out
// N=100000, E=1600000, IN=128, D=64.
//
// R2/R3: replaced f32-atomic scatter (13 ns/atomic, 2x1355us) with per-call
// CSR build (int histogram + scan + fill) and an atomic-free register gather.
// (R3 is an unchanged resubmit after an infra failure.)

// ---------------------------------------------------------------------------
// Node GEMM: out[N,64] = act((A [+ A2])[N,K] @ W[64,K]^T + bias)
// ---------------------------------------------------------------------------
template <int K, int RPT>
__global__ __launch_bounds__(256) void gemm_nodes(
    const float* __restrict__ A, const float* __restrict__ A2,
    const float* __restrict__ W, const float* __restrict__ bias,
    float* __restrict__ out, int N, int relu)
{
    constexpr int ROWS = 16 * RPT;
    __shared__ float xs[ROWS][K + 1];
    __shared__ float wt[K * 64];

    const int tid = threadIdx.x;

    for (int idx = tid; idx < 64 * K; idx += 256) {
        const int j = idx >> (K == 128 ? 7 : 6);
        const int k = idx & (K - 1);
        wt[k * 64 + j] = W[idx];
    }

    const int base = blockIdx.x * ROWS;
    constexpr int Q = K / 4;
    for (int i4 = tid; i4 < ROWS * Q; i4 += 256) {
        const int r = i4 / Q;
        const int q = i4 - r * Q;
        int row = base + r;
        if (row > N - 1) row = N - 1;
        float4 v = *(const float4*)(A + (size_t)row * K + q * 4);
        if (A2) {
            const float4 vb = *(const float4*)(A2 + (size_t)row * K + q * 4);
            v.x += vb.x; v.y += vb.y; v.z += vb.z; v.w += vb.w;
        }
        float* p = &xs[r][q * 4];
        p[0] = v.x; p[1] = v.y; p[2] = v.z; p[3] = v.w;
    }
    __syncthreads();

    const int cg = tid & 15;
    const int rs = tid >> 4;

    float acc[RPT][4];
    const float4 bv = *(const float4*)(bias + 4 * cg);
#pragma unroll
    for (int i = 0; i < RPT; ++i) {
        acc[i][0] = bv.x; acc[i][1] = bv.y; acc[i][2] = bv.z; acc[i][3] = bv.w;
    }

#pragma unroll
    for (int k = 0; k < K; ++k) {
        const float4 w4 = *(const float4*)&wt[k * 64 + 4 * cg];
#pragma unroll
        for (int i = 0; i < RPT; ++i) {
            const float a = xs[rs + 16 * i][k];
            acc[i][0] += a * w4.x;
            acc[i][1] += a * w4.y;
            acc[i][2] += a * w4.z;
            acc[i][3] += a * w4.w;
        }
    }

#pragma unroll
    for (int i = 0; i < RPT; ++i) {
        const int row = base + rs + 16 * i;
        if (row < N) {
            float4 r4 = make_float4(acc[i][0], acc[i][1], acc[i][2], acc[i][3]);
            if (relu) {
                r4.x = fmaxf(r4.x, 0.f); r4.y = fmaxf(r4.y, 0.f);
                r4.z = fmaxf(r4.z, 0.f); r4.w = fmaxf(r4.w, 0.f);
            }
            *(float4*)(out + (size_t)row * 64 + 4 * cg) = r4;
        }
    }
}

// ---------------------------------------------------------------------------
// CSR build: deg histogram -> 3-phase exclusive scan -> cursor fill.
// ---------------------------------------------------------------------------
__global__ __launch_bounds__(256) void k_hist(
    const int* __restrict__ dst, int* __restrict__ deg, int E)
{
    const int e = blockIdx.x * 256 + threadIdx.x;
    if (e < E) atomicAdd(&deg[dst[e]], 1);
}

__global__ __launch_bounds__(256) void k_blocksum(
    const int* __restrict__ deg, int* __restrict__ partial, int N)
{
    __shared__ int s[256];
    const int i = blockIdx.x * 256 + threadIdx.x;
    s[threadIdx.x] = (i < N) ? deg[i] : 0;
    __syncthreads();
    for (int off = 128; off > 0; off >>= 1) {
        if (threadIdx.x < off) s[threadIdx.x] += s[threadIdx.x + off];
        __syncthreads();
    }
    if (threadIdx.x == 0) partial[blockIdx.x] = s[0];
}

__global__ __launch_bounds__(512) void k_scanpartial(
    int* __restrict__ partial, int nblk)
{
    __shared__ int s[512];
    const int t = threadIdx.x;
    s[t] = (t < nblk) ? partial[t] : 0;
    __syncthreads();
    for (int off = 1; off < 512; off <<= 1) {
        const int v = (t >= off) ? s[t - off] : 0;
        __syncthreads();
        s[t] += v;
        __syncthreads();
    }
    if (t < nblk) partial[t] = (t == 0) ? 0 : s[t - 1];
}

__global__ __launch_bounds__(256) void k_offsets(
    const int* __restrict__ deg, const int* __restrict__ partial,
    int* __restrict__ offs, int* __restrict__ cursor, int N)
{
    __shared__ int s[256];
    const int i = blockIdx.x * 256 + threadIdx.x;
    const int t = threadIdx.x;
    const int v = (i < N) ? deg[i] : 0;
    s[t] = v;
    __syncthreads();
    for (int off = 1; off < 256; off <<= 1) {
        const int u = (t >= off) ? s[t - off] : 0;
        __syncthreads();
        s[t] += u;
        __syncthreads();
    }
    const int o = partial[blockIdx.x] + s[t] - v;   // exclusive
    if (i < N) {
        offs[i] = o;
        cursor[i] = o;
        if (i == N - 1) offs[N] = o + v;
    }
}

__global__ __launch_bounds__(256) void k_fill(
    const int* __restrict__ src, const int* __restrict__ dst,
    int* __restrict__ cursor, int* __restrict__ slots, int E)
{
    const int e = blockIdx.x * 256 + threadIdx.x;
    if (e >= E) return;
    const int pos = atomicAdd(&cursor[dst[e]], 1);
    slots[pos] = src[e];
}

// ---------------------------------------------------------------------------
// Atomic-free aggregation: 16 lanes per node, lane owns 4 feature cols.
// agg[n] = sum over in-edges of h[src]; full overwrite (no memset needed).
// ---------------------------------------------------------------------------
__global__ __launch_bounds__(256) void gather_sum(
    const float* __restrict__ h, const int* __restrict__ slots,
    const int* __restrict__ offs, float* __restrict__ agg, int N)
{
    const int g = blockIdx.x * 256 + threadIdx.x;
    const int n = g >> 4;
    if (n >= N) return;
    const int q = (g & 15) * 4;
    const int beg = offs[n];
    const int end = offs[n + 1];
    float4 acc = make_float4(0.f, 0.f, 0.f, 0.f);
    int j = beg;
    for (; j + 2 <= end; j += 2) {          // 2-deep to overlap row fetches
        const int s0 = slots[j];
        const int s1 = slots[j + 1];
        const float4 v0 = *(const float4*)(h + (size_t)s0 * 64 + q);
        const float4 v1 = *(const float4*)(h + (size_t)s1 * 64 + q);
        acc.x += v0.x + v1.x; acc.y += v0.y + v1.y;
        acc.z += v0.z + v1.z; acc.w += v0.w + v1.w;
    }
    if (j < end) {
        const int s0 = slots[j];
        const float4 v0 = *(const float4*)(h + (size_t)s0 * 64 + q);
        acc.x += v0.x; acc.y += v0.y; acc.z += v0.z; acc.w += v0.w;
    }
    *(float4*)(agg + (size_t)n * 64 + q) = acc;
}

extern "C" void kernel_launch(void* const* d_in, const int* in_sizes, int n_in,
                              void* d_out, int out_size, void* d_ws, size_t ws_size,
                              hipStream_t stream)
{
    const float* x       = (const float*)d_in[0];
    const int*   ei      = (const int*)  d_in[1];
    const float* W_pre   = (const float*)d_in[2];
    const float* b_pre   = (const float*)d_in[3];
    const float* W_first = (const float*)d_in[4];
    const float* b_first = (const float*)d_in[5];
    const float* W_out   = (const float*)d_in[6];
    const float* b_out   = (const float*)d_in[7];

    const int N = in_sizes[0] / 128;
    const int E = in_sizes[1] / 2;
    const int* src = ei;
    const int* dst = ei + E;

    // Workspace layout (~33.2 MB):
    float* h     = (float*)d_ws;                 // [N,64]
    int*   slots = (int*)(h + (size_t)N * 64);   // [E]  sorted src ids
    int*   deg   = slots + E;                    // [N]
    int*   offs  = deg + N;                      // [N+1]
    int*   cursor= offs + N + 1;                 // [N]
    int*   partial = cursor + N;                 // [nblk]

    float* agg = (float*)d_out;                  // d_out doubles as agg scratch
    float* out = (float*)d_out;

    const int nblk        = (N + 255) / 256;     // 391 (<=512 for scanpartial)
    const int edge_blocks = (E + 255) / 256;     // 6250
    const int node16_blocks = (N * 16 + 255) / 256;
    const int gemm_pre_blocks  = (N + 31) / 32;
    const int gemm_conv_blocks = (N + 63) / 64;

    // --- CSR build (independent of h) ---
    hipMemsetAsync(deg, 0, (size_t)N * sizeof(int), stream);
    k_hist<<<edge_blocks, 256, 0, stream>>>(dst, deg, E);
    k_blocksum<<<nblk, 256, 0, stream>>>(deg, partial, N);
    k_scanpartial<<<1, 512, 0, stream>>>(partial, nblk);
    k_offsets<<<nblk, 256, 0, stream>>>(deg, partial, offs, cursor, N);
    k_fill<<<edge_blocks, 256, 0, stream>>>(src, dst, cursor, slots, E);

    // --- 1. h = x @ W_pre.T + b_pre ---
    gemm_nodes<128, 2><<<gemm_pre_blocks, 256, 0, stream>>>(
        x, nullptr, W_pre, b_pre, h, N, 0);

    // --- 2. agg = seg_sum(h[src]); h = relu((h+agg)@W_first.T + b_first) ---
    gather_sum<<<node16_blocks, 256, 0, stream>>>(h, slots, offs, agg, N);
    gemm_nodes<64, 4><<<gemm_conv_blocks, 256, 0, stream>>>(
        h, agg, W_first, b_first, h, N, 1);

    // --- 3. agg = seg_sum(h[src]); out = (h+agg)@W_out.T + b_out ---
    gather_sum<<<node16_blocks, 256, 0, stream>>>(h, slots, offs, agg, N);
    gemm_nodes<64, 4><<<gemm_conv_blocks, 256, 0, stream>>>(
        h, agg, W_out, b_out, out, N, 0);
}

// Round 4
// 415.582 us; speedup vs baseline: 7.7288x; 1.9506x over previous
//
#include <hip/hip_runtime.h>

// GIN forward: h = x@W_pre.T + b_pre
//              h = relu((h + seg_sum(h[src]->dst)) @ W_first.T + b_first)
//              out = (h + seg_sum(h[src]->dst)) @ W_out.T + b_out
// N=100000, E=1600000, IN=128, D=64.
//
// R4: fix GEMM register spilling (VGPR=256, ~900MB scratch traffic/dispatch)
// by capping k-loop unroll at 4, and kill the 64-way LDS bank conflict on the
// W-transpose staging with a 16B-group XOR swizzle (read stays ds_read_b128).

// ---------------------------------------------------------------------------
// Node GEMM: out[N,64] = act((A [+ A2])[N,K] @ W[64,K]^T + bias)
// wt swizzle: W[j][k] lives at wt[k*64 + (((j>>2) ^ (k&15))<<2) + (j&3)].
// Read of cols 4cg..4cg+3 at depth k: float4 at wt[k*64 + ((cg^(k&15))<<2)]
// -> 16 distinct aligned 16B chunks per wave = conflict-free.
// ---------------------------------------------------------------------------
template <int K, int RPT>
__global__ __launch_bounds__(256) void gemm_nodes(
    const float* __restrict__ A, const float* __restrict__ A2,
    const float* __restrict__ W, const float* __restrict__ bias,
    float* __restrict__ out, int N, int relu)
{
    constexpr int ROWS = 16 * RPT;
    __shared__ float xs[ROWS][K + 1];
    __shared__ float wt[K * 64];

    const int tid = threadIdx.x;

    // Stage W[64][K] transposed+swizzled (coalesced global reads).
    for (int idx = tid; idx < 64 * K; idx += 256) {
        const int j = idx >> (K == 128 ? 7 : 6);
        const int k = idx & (K - 1);
        const int g = (j >> 2) ^ (k & 15);
        wt[k * 64 + (g << 2) + (j & 3)] = W[idx];
    }

    // Stage x tile (optionally + A2) with float4 loads.
    const int base = blockIdx.x * ROWS;
    constexpr int Q = K / 4;
    for (int i4 = tid; i4 < ROWS * Q; i4 += 256) {
        const int r = i4 / Q;
        const int q = i4 - r * Q;
        int row = base + r;
        if (row > N - 1) row = N - 1;
        float4 v = *(const float4*)(A + (size_t)row * K + q * 4);
        if (A2) {
            const float4 vb = *(const float4*)(A2 + (size_t)row * K + q * 4);
            v.x += vb.x; v.y += vb.y; v.z += vb.z; v.w += vb.w;
        }
        float* p = &xs[r][q * 4];
        p[0] = v.x; p[1] = v.y; p[2] = v.z; p[3] = v.w;
    }
    __syncthreads();

    const int cg = tid & 15;
    const int rs = tid >> 4;

    float acc[RPT][4];
    const float4 bv = *(const float4*)(bias + 4 * cg);
#pragma unroll
    for (int i = 0; i < RPT; ++i) {
        acc[i][0] = bv.x; acc[i][1] = bv.y; acc[i][2] = bv.z; acc[i][3] = bv.w;
    }

#pragma unroll 4
    for (int k = 0; k < K; ++k) {
        const float4 w4 = *(const float4*)&wt[k * 64 + ((cg ^ (k & 15)) << 2)];
#pragma unroll
        for (int i = 0; i < RPT; ++i) {
            const float a = xs[rs + 16 * i][k];
            acc[i][0] += a * w4.x;
            acc[i][1] += a * w4.y;
            acc[i][2] += a * w4.z;
            acc[i][3] += a * w4.w;
        }
    }

#pragma unroll
    for (int i = 0; i < RPT; ++i) {
        const int row = base + rs + 16 * i;
        if (row < N) {
            float4 r4 = make_float4(acc[i][0], acc[i][1], acc[i][2], acc[i][3]);
            if (relu) {
                r4.x = fmaxf(r4.x, 0.f); r4.y = fmaxf(r4.y, 0.f);
                r4.z = fmaxf(r4.z, 0.f); r4.w = fmaxf(r4.w, 0.f);
            }
            *(float4*)(out + (size_t)row * 64 + 4 * cg) = r4;
        }
    }
}

// ---------------------------------------------------------------------------
// CSR build: deg histogram -> 3-phase exclusive scan -> cursor fill.
// ---------------------------------------------------------------------------
__global__ __launch_bounds__(256) void k_hist(
    const int* __restrict__ dst, int* __restrict__ deg, int E)
{
    const int e = blockIdx.x * 256 + threadIdx.x;
    if (e < E) atomicAdd(&deg[dst[e]], 1);
}

__global__ __launch_bounds__(256) void k_blocksum(
    const int* __restrict__ deg, int* __restrict__ partial, int N)
{
    __shared__ int s[256];
    const int i = blockIdx.x * 256 + threadIdx.x;
    s[threadIdx.x] = (i < N) ? deg[i] : 0;
    __syncthreads();
    for (int off = 128; off > 0; off >>= 1) {
        if (threadIdx.x < off) s[threadIdx.x] += s[threadIdx.x + off];
        __syncthreads();
    }
    if (threadIdx.x == 0) partial[blockIdx.x] = s[0];
}

__global__ __launch_bounds__(512) void k_scanpartial(
    int* __restrict__ partial, int nblk)
{
    __shared__ int s[512];
    const int t = threadIdx.x;
    s[t] = (t < nblk) ? partial[t] : 0;
    __syncthreads();
    for (int off = 1; off < 512; off <<= 1) {
        const int v = (t >= off) ? s[t - off] : 0;
        __syncthreads();
        s[t] += v;
        __syncthreads();
    }
    if (t < nblk) partial[t] = (t == 0) ? 0 : s[t - 1];
}

__global__ __launch_bounds__(256) void k_offsets(
    const int* __restrict__ deg, const int* __restrict__ partial,
    int* __restrict__ offs, int* __restrict__ cursor, int N)
{
    __shared__ int s[256];
    const int i = blockIdx.x * 256 + threadIdx.x;
    const int t = threadIdx.x;
    const int v = (i < N) ? deg[i] : 0;
    s[t] = v;
    __syncthreads();
    for (int off = 1; off < 256; off <<= 1) {
        const int u = (t >= off) ? s[t - off] : 0;
        __syncthreads();
        s[t] += u;
        __syncthreads();
    }
    const int o = partial[blockIdx.x] + s[t] - v;   // exclusive
    if (i < N) {
        offs[i] = o;
        cursor[i] = o;
        if (i == N - 1) offs[N] = o + v;
    }
}

__global__ __launch_bounds__(256) void k_fill(
    const int* __restrict__ src, const int* __restrict__ dst,
    int* __restrict__ cursor, int* __restrict__ slots, int E)
{
    const int e = blockIdx.x * 256 + threadIdx.x;
    if (e >= E) return;
    const int pos = atomicAdd(&cursor[dst[e]], 1);
    slots[pos] = src[e];
}

// ---------------------------------------------------------------------------
// Atomic-free aggregation: 16 lanes per node, lane owns 4 feature cols.
// ---------------------------------------------------------------------------
__global__ __launch_bounds__(256) void gather_sum(
    const float* __restrict__ h, const int* __restrict__ slots,
    const int* __restrict__ offs, float* __restrict__ agg, int N)
{
    const int g = blockIdx.x * 256 + threadIdx.x;
    const int n = g >> 4;
    if (n >= N) return;
    const int q = (g & 15) * 4;
    const int beg = offs[n];
    const int end = offs[n + 1];
    float4 acc = make_float4(0.f, 0.f, 0.f, 0.f);
    int j = beg;
    for (; j + 2 <= end; j += 2) {
        const int s0 = slots[j];
        const int s1 = slots[j + 1];
        const float4 v0 = *(const float4*)(h + (size_t)s0 * 64 + q);
        const float4 v1 = *(const float4*)(h + (size_t)s1 * 64 + q);
        acc.x += v0.x + v1.x; acc.y += v0.y + v1.y;
        acc.z += v0.z + v1.z; acc.w += v0.w + v1.w;
    }
    if (j < end) {
        const int s0 = slots[j];
        const float4 v0 = *(const float4*)(h + (size_t)s0 * 64 + q);
        acc.x += v0.x; acc.y += v0.y; acc.z += v0.z; acc.w += v0.w;
    }
    *(float4*)(agg + (size_t)n * 64 + q) = acc;
}

extern "C" void kernel_launch(void* const* d_in, const int* in_sizes, int n_in,
                              void* d_out, int out_size, void* d_ws, size_t ws_size,
                              hipStream_t stream)
{
    const float* x       = (const float*)d_in[0];
    const int*   ei      = (const int*)  d_in[1];
    const float* W_pre   = (const float*)d_in[2];
    const float* b_pre   = (const float*)d_in[3];
    const float* W_first = (const float*)d_in[4];
    const float* b_first = (const float*)d_in[5];
    const float* W_out   = (const float*)d_in[6];
    const float* b_out   = (const float*)d_in[7];

    const int N = in_sizes[0] / 128;
    const int E = in_sizes[1] / 2;
    const int* src = ei;
    const int* dst = ei + E;

    // Workspace layout (~33.2 MB):
    float* h     = (float*)d_ws;                 // [N,64]
    int*   slots = (int*)(h + (size_t)N * 64);   // [E]
    int*   deg   = slots + E;                    // [N]
    int*   offs  = deg + N;                      // [N+1]
    int*   cursor= offs + N + 1;                 // [N]
    int*   partial = cursor + N;                 // [nblk]

    float* agg = (float*)d_out;                  // d_out doubles as agg scratch
    float* out = (float*)d_out;

    const int nblk          = (N + 255) / 256;   // 391 (<=512 for scanpartial)
    const int edge_blocks   = (E + 255) / 256;
    const int node16_blocks = (N * 16 + 255) / 256;
    const int gemm_pre_blocks  = (N + 31) / 32;
    const int gemm_conv_blocks = (N + 63) / 64;

    // --- CSR build (independent of h) ---
    hipMemsetAsync(deg, 0, (size_t)N * sizeof(int), stream);
    k_hist<<<edge_blocks, 256, 0, stream>>>(dst, deg, E);
    k_blocksum<<<nblk, 256, 0, stream>>>(deg, partial, N);
    k_scanpartial<<<1, 512, 0, stream>>>(partial, nblk);
    k_offsets<<<nblk, 256, 0, stream>>>(deg, partial, offs, cursor, N);
    k_fill<<<edge_blocks, 256, 0, stream>>>(src, dst, cursor, slots, E);

    // --- 1. h = x @ W_pre.T + b_pre ---
    gemm_nodes<128, 2><<<gemm_pre_blocks, 256, 0, stream>>>(
        x, nullptr, W_pre, b_pre, h, N, 0);

    // --- 2. agg = seg_sum(h[src]); h = relu((h+agg)@W_first.T + b_first) ---
    gather_sum<<<node16_blocks, 256, 0, stream>>>(h, slots, offs, agg, N);
    gemm_nodes<64, 4><<<gemm_conv_blocks, 256, 0, stream>>>(
        h, agg, W_first, b_first, h, N, 1);

    // --- 3. agg = seg_sum(h[src]); out = (h+agg)@W_out.T + b_out ---
    gather_sum<<<node16_blocks, 256, 0, stream>>>(h, slots, offs, agg, N);
    gemm_nodes<64, 4><<<gemm_conv_blocks, 256, 0, stream>>>(
        h, agg, W_out, b_out, out, N, 0);
}

// Round 5
// 252.419 us; speedup vs baseline: 12.7247x; 1.6464x over previous
//
#include <hip/hip_runtime.h>

// GIN forward: h = x@W_pre.T + b_pre
//              h = relu((h + seg_sum(h[src]->dst)) @ W_first.T + b_first)
//              out = (h + seg_sum(h[src]->dst)) @ W_out.T + b_out
// N=100000, E=1600000, IN=128, D=64.
//
// R5: CSR build rewritten as 2-level counting sort with LDS-staged coalesced
// writes. Old k_fill did 1.6M random 4B stores -> 105MB of 64B-granule HBM
// write traffic at 790 GB/s (133us). New path: bucket-sort by dst>>8 (packed
// (dstLocal<<24)|src), then per-bucket LDS sort + coalesced writeback.

// ---------------------------------------------------------------------------
// Node GEMM: out[N,64] = act((A [+ A2])[N,K] @ W[64,K]^T + bias)
// wt swizzle: W[j][k] at wt[k*64 + (((j>>2)^(k&15))<<2) + (j&3)]; read is a
// conflict-free aligned ds_read_b128. Unroll capped at 4 (VGPR budget).
// ---------------------------------------------------------------------------
template <int K, int RPT>
__global__ __launch_bounds__(256) void gemm_nodes(
    const float* __restrict__ A, const float* __restrict__ A2,
    const float* __restrict__ W, const float* __restrict__ bias,
    float* __restrict__ out, int N, int relu)
{
    constexpr int ROWS = 16 * RPT;
    __shared__ float xs[ROWS][K + 1];
    __shared__ float wt[K * 64];

    const int tid = threadIdx.x;

    for (int idx = tid; idx < 64 * K; idx += 256) {
        const int j = idx >> (K == 128 ? 7 : 6);
        const int k = idx & (K - 1);
        const int g = (j >> 2) ^ (k & 15);
        wt[k * 64 + (g << 2) + (j & 3)] = W[idx];
    }

    const int base = blockIdx.x * ROWS;
    constexpr int Q = K / 4;
    for (int i4 = tid; i4 < ROWS * Q; i4 += 256) {
        const int r = i4 / Q;
        const int q = i4 - r * Q;
        int row = base + r;
        if (row > N - 1) row = N - 1;
        float4 v = *(const float4*)(A + (size_t)row * K + q * 4);
        if (A2) {
            const float4 vb = *(const float4*)(A2 + (size_t)row * K + q * 4);
            v.x += vb.x; v.y += vb.y; v.z += vb.z; v.w += vb.w;
        }
        float* p = &xs[r][q * 4];
        p[0] = v.x; p[1] = v.y; p[2] = v.z; p[3] = v.w;
    }
    __syncthreads();

    const int cg = tid & 15;
    const int rs = tid >> 4;

    float acc[RPT][4];
    const float4 bv = *(const float4*)(bias + 4 * cg);
#pragma unroll
    for (int i = 0; i < RPT; ++i) {
        acc[i][0] = bv.x; acc[i][1] = bv.y; acc[i][2] = bv.z; acc[i][3] = bv.w;
    }

#pragma unroll 4
    for (int k = 0; k < K; ++k) {
        const float4 w4 = *(const float4*)&wt[k * 64 + ((cg ^ (k & 15)) << 2)];
#pragma unroll
        for (int i = 0; i < RPT; ++i) {
            const float a = xs[rs + 16 * i][k];
            acc[i][0] += a * w4.x;
            acc[i][1] += a * w4.y;
            acc[i][2] += a * w4.z;
            acc[i][3] += a * w4.w;
        }
    }

#pragma unroll
    for (int i = 0; i < RPT; ++i) {
        const int row = base + rs + 16 * i;
        if (row < N) {
            float4 r4 = make_float4(acc[i][0], acc[i][1], acc[i][2], acc[i][3]);
            if (relu) {
                r4.x = fmaxf(r4.x, 0.f); r4.y = fmaxf(r4.y, 0.f);
                r4.z = fmaxf(r4.z, 0.f); r4.w = fmaxf(r4.w, 0.f);
            }
            *(float4*)(out + (size_t)row * 64 + 4 * cg) = r4;
        }
    }
}

// ---------------------------------------------------------------------------
// CSR build via 2-level counting sort.
// CHUNK=4096 edges/block; buckets = dst>>8 (256 nodes each).
// ---------------------------------------------------------------------------
constexpr int CHUNK = 4096;

// Pass A: per-chunk bucket histogram -> counts[b*NC + c]
__global__ __launch_bounds__(256) void p_hist(
    const int* __restrict__ dst, int* __restrict__ counts,
    int E, int NBK, int NC)
{
    __shared__ int cnt[512];
    const int c = blockIdx.x;
    for (int b = threadIdx.x; b < NBK; b += 256) cnt[b] = 0;
    __syncthreads();
    const int beg = c * CHUNK;
    const int end = min(beg + CHUNK, E);
    for (int e = beg + threadIdx.x; e < end; e += 256)
        atomicAdd(&cnt[dst[e] >> 8], 1);
    __syncthreads();
    for (int b = threadIdx.x; b < NBK; b += 256)
        counts[b * NC + c] = cnt[b];
}

// Generic scan helpers over the counts array (n = NBK*NC).
__global__ __launch_bounds__(256) void k_blocksum(
    const int* __restrict__ in, int* __restrict__ partial, int n)
{
    __shared__ int s[256];
    const int i = blockIdx.x * 256 + threadIdx.x;
    s[threadIdx.x] = (i < n) ? in[i] : 0;
    __syncthreads();
    for (int off = 128; off > 0; off >>= 1) {
        if (threadIdx.x < off) s[threadIdx.x] += s[threadIdx.x + off];
        __syncthreads();
    }
    if (threadIdx.x == 0) partial[blockIdx.x] = s[0];
}

__global__ __launch_bounds__(1024) void k_scanpartial1024(
    int* __restrict__ partial, int nblk)
{
    __shared__ int s[1024];
    const int t = threadIdx.x;
    s[t] = (t < nblk) ? partial[t] : 0;
    __syncthreads();
    for (int off = 1; off < 1024; off <<= 1) {
        const int v = (t >= off) ? s[t - off] : 0;
        __syncthreads();
        s[t] += v;
        __syncthreads();
    }
    if (t < nblk) partial[t] = (t == 0) ? 0 : s[t - 1];
}

__global__ __launch_bounds__(256) void k_exscan(
    int* __restrict__ data, const int* __restrict__ partial, int n)
{
    __shared__ int s[256];
    const int i = blockIdx.x * 256 + threadIdx.x;
    const int t = threadIdx.x;
    const int v = (i < n) ? data[i] : 0;
    s[t] = v;
    __syncthreads();
    for (int off = 1; off < 256; off <<= 1) {
        const int u = (t >= off) ? s[t - off] : 0;
        __syncthreads();
        s[t] += u;
        __syncthreads();
    }
    if (i < n) data[i] = partial[blockIdx.x] + s[t] - v;   // exclusive
}

// Pass C: scatter edges into bucket-contiguous regions, packed.
__global__ __launch_bounds__(256) void p_scatter(
    const int* __restrict__ src, const int* __restrict__ dst,
    const int* __restrict__ counts, unsigned* __restrict__ slots,
    int E, int NBK, int NC)
{
    __shared__ int cur[512];
    const int c = blockIdx.x;
    for (int b = threadIdx.x; b < NBK; b += 256) cur[b] = counts[b * NC + c];
    __syncthreads();
    const int beg = c * CHUNK;
    const int end = min(beg + CHUNK, E);
    for (int e = beg + threadIdx.x; e < end; e += 256) {
        const int d = dst[e];
        const int pos = atomicAdd(&cur[d >> 8], 1);
        slots[pos] = ((unsigned)(d & 255) << 24) | (unsigned)src[e];
    }
}

// Pass D: per-bucket local node sort (in LDS), write offs + final slots (src
// only), fully coalesced. scratch (= d_out area) used only on >8192 overflow.
__global__ __launch_bounds__(256) void p_bucket(
    unsigned* __restrict__ slots, const int* __restrict__ counts,
    int* __restrict__ offs, unsigned* __restrict__ scratch,
    int E, int N, int NBK, int NC)
{
    __shared__ int cnt[256];
    __shared__ int noff[256];
    __shared__ unsigned outl[8192];
    const int b = blockIdx.x;
    const int t = threadIdx.x;
    const int base = counts[b * NC];
    const int next = (b == NBK - 1) ? E : counts[(b + 1) * NC];
    const int size = next - base;

    cnt[t] = 0;
    __syncthreads();
    for (int i = t; i < size; i += 256)
        atomicAdd(&cnt[slots[base + i] >> 24], 1);
    __syncthreads();

    // exclusive scan of cnt -> noff; cnt becomes cursor
    const int v = cnt[t];
    noff[t] = v;
    __syncthreads();
    for (int off = 1; off < 256; off <<= 1) {
        const int u = (t >= off) ? noff[t - off] : 0;
        __syncthreads();
        noff[t] += u;
        __syncthreads();
    }
    const int ex = noff[t] - v;
    __syncthreads();
    noff[t] = ex;
    cnt[t] = ex;
    __syncthreads();

    const int node = (b << 8) + t;
    if (node <= N) offs[node] = base + noff[t];

    if (size <= 8192) {
        for (int i = t; i < size; i += 256) {
            const unsigned p = slots[base + i];
            const int pos = atomicAdd(&cnt[p >> 24], 1);
            outl[pos] = p & 0x00FFFFFFu;
        }
        __syncthreads();
        for (int i = t; i < size; i += 256) slots[base + i] = outl[i];
    } else {
        // overflow fallback (statistically unreachable for uniform dst)
        for (int i = t; i < size; i += 256) scratch[base + i] = slots[base + i];
        __threadfence();
        __syncthreads();
        for (int i = t; i < size; i += 256) {
            const unsigned p = scratch[base + i];
            const int pos = atomicAdd(&cnt[p >> 24], 1);
            slots[base + pos] = p & 0x00FFFFFFu;
        }
    }
}

// ---------------------------------------------------------------------------
// Atomic-free aggregation: 16 lanes per node, lane owns 4 feature cols.
// ---------------------------------------------------------------------------
__global__ __launch_bounds__(256) void gather_sum(
    const float* __restrict__ h, const int* __restrict__ slots,
    const int* __restrict__ offs, float* __restrict__ agg, int N)
{
    const int g = blockIdx.x * 256 + threadIdx.x;
    const int n = g >> 4;
    if (n >= N) return;
    const int q = (g & 15) * 4;
    const int beg = offs[n];
    const int end = offs[n + 1];
    float4 acc = make_float4(0.f, 0.f, 0.f, 0.f);
    int j = beg;
    for (; j + 2 <= end; j += 2) {
        const int s0 = slots[j];
        const int s1 = slots[j + 1];
        const float4 v0 = *(const float4*)(h + (size_t)s0 * 64 + q);
        const float4 v1 = *(const float4*)(h + (size_t)s1 * 64 + q);
        acc.x += v0.x + v1.x; acc.y += v0.y + v1.y;
        acc.z += v0.z + v1.z; acc.w += v0.w + v1.w;
    }
    if (j < end) {
        const int s0 = slots[j];
        const float4 v0 = *(const float4*)(h + (size_t)s0 * 64 + q);
        acc.x += v0.x; acc.y += v0.y; acc.z += v0.z; acc.w += v0.w;
    }
    *(float4*)(agg + (size_t)n * 64 + q) = acc;
}

extern "C" void kernel_launch(void* const* d_in, const int* in_sizes, int n_in,
                              void* d_out, int out_size, void* d_ws, size_t ws_size,
                              hipStream_t stream)
{
    const float* x       = (const float*)d_in[0];
    const int*   ei      = (const int*)  d_in[1];
    const float* W_pre   = (const float*)d_in[2];
    const float* b_pre   = (const float*)d_in[3];
    const float* W_first = (const float*)d_in[4];
    const float* b_first = (const float*)d_in[5];
    const float* W_out   = (const float*)d_in[6];
    const float* b_out   = (const float*)d_in[7];

    const int N = in_sizes[0] / 128;
    const int E = in_sizes[1] / 2;
    const int* src = ei;
    const int* dst = ei + E;

    const int NBK = (N >> 8) + 1;                 // buckets of 256 nodes, covers node N
    const int NC  = (E + CHUNK - 1) / CHUNK;      // chunks
    const int nscan = NBK * NC;
    const int nsblk = (nscan + 255) / 256;        // <= 1024 for these sizes

    // Workspace layout (~33 MB):
    float*    h      = (float*)d_ws;              // [N,64]
    unsigned* slots  = (unsigned*)(h + (size_t)N * 64);   // [E]
    int*      counts = (int*)(slots + E);         // [NBK*NC]
    int*      partial= counts + nscan;            // [<=1024]
    int*      offs   = partial + 1024;            // [N+1]

    float* agg = (float*)d_out;                   // d_out doubles as agg scratch
    float* out = (float*)d_out;

    const int node16_blocks    = (N * 16 + 255) / 256;
    const int gemm_pre_blocks  = (N + 31) / 32;
    const int gemm_conv_blocks = (N + 63) / 64;

    // --- CSR build (counting sort; d_out free as overflow scratch here) ---
    p_hist<<<NC, 256, 0, stream>>>(dst, counts, E, NBK, NC);
    k_blocksum<<<nsblk, 256, 0, stream>>>(counts, partial, nscan);
    k_scanpartial1024<<<1, 1024, 0, stream>>>(partial, nsblk);
    k_exscan<<<nsblk, 256, 0, stream>>>(counts, partial, nscan);
    p_scatter<<<NC, 256, 0, stream>>>(src, dst, counts, slots, E, NBK, NC);
    p_bucket<<<NBK, 256, 0, stream>>>(slots, counts, offs, (unsigned*)d_out,
                                      E, N, NBK, NC);

    // --- 1. h = x @ W_pre.T + b_pre ---
    gemm_nodes<128, 2><<<gemm_pre_blocks, 256, 0, stream>>>(
        x, nullptr, W_pre, b_pre, h, N, 0);

    // --- 2. agg = seg_sum(h[src]); h = relu((h+agg)@W_first.T + b_first) ---
    gather_sum<<<node16_blocks, 256, 0, stream>>>(h, (const int*)slots, offs, agg, N);
    gemm_nodes<64, 4><<<gemm_conv_blocks, 256, 0, stream>>>(
        h, agg, W_first, b_first, h, N, 1);

    // --- 3. agg = seg_sum(h[src]); out = (h+agg)@W_out.T + b_out ---
    gather_sum<<<node16_blocks, 256, 0, stream>>>(h, (const int*)slots, offs, agg, N);
    gemm_nodes<64, 4><<<gemm_conv_blocks, 256, 0, stream>>>(
        h, agg, W_out, b_out, out, N, 0);
}

// Round 6
// 242.960 us; speedup vs baseline: 13.2201x; 1.0389x over previous
//
#include <hip/hip_runtime.h>

// GIN forward: h = x@W_pre.T + b_pre
//              h = relu((h + seg_sum(h[src]->dst)) @ W_first.T + b_first)
//              out = (h + seg_sum(h[src]->dst)) @ W_out.T + b_out
// N=100000, E=1600000, IN=128, D=64.
//
// R6: gather loop 4-deep (4 independent h-row loads in flight; R5 showed
// latency-bound: 3.5TB/s L2-miss BW at VALUBusy 12%), and conv2 fused into a
// single gather+add+GEMM kernel (removes agg2 write + (h+agg) re-read).

// ---------------------------------------------------------------------------
// Node GEMM: out[N,64] = act((A [+ A2])[N,K] @ W[64,K]^T + bias)
// wt swizzle: W[j][k] at wt[k*64 + (((j>>2)^(k&15))<<2) + (j&3)]; read is a
// conflict-free aligned ds_read_b128. Unroll capped at 4 (VGPR budget).
// ---------------------------------------------------------------------------
template <int K, int RPT>
__global__ __launch_bounds__(256) void gemm_nodes(
    const float* __restrict__ A, const float* __restrict__ A2,
    const float* __restrict__ W, const float* __restrict__ bias,
    float* __restrict__ out, int N, int relu)
{
    constexpr int ROWS = 16 * RPT;
    __shared__ float xs[ROWS][K + 1];
    __shared__ float wt[K * 64];

    const int tid = threadIdx.x;

    for (int idx = tid; idx < 64 * K; idx += 256) {
        const int j = idx >> (K == 128 ? 7 : 6);
        const int k = idx & (K - 1);
        const int g = (j >> 2) ^ (k & 15);
        wt[k * 64 + (g << 2) + (j & 3)] = W[idx];
    }

    const int base = blockIdx.x * ROWS;
    constexpr int Q = K / 4;
    for (int i4 = tid; i4 < ROWS * Q; i4 += 256) {
        const int r = i4 / Q;
        const int q = i4 - r * Q;
        int row = base + r;
        if (row > N - 1) row = N - 1;
        float4 v = *(const float4*)(A + (size_t)row * K + q * 4);
        if (A2) {
            const float4 vb = *(const float4*)(A2 + (size_t)row * K + q * 4);
            v.x += vb.x; v.y += vb.y; v.z += vb.z; v.w += vb.w;
        }
        float* p = &xs[r][q * 4];
        p[0] = v.x; p[1] = v.y; p[2] = v.z; p[3] = v.w;
    }
    __syncthreads();

    const int cg = tid & 15;
    const int rs = tid >> 4;

    float acc[RPT][4];
    const float4 bv = *(const float4*)(bias + 4 * cg);
#pragma unroll
    for (int i = 0; i < RPT; ++i) {
        acc[i][0] = bv.x; acc[i][1] = bv.y; acc[i][2] = bv.z; acc[i][3] = bv.w;
    }

#pragma unroll 4
    for (int k = 0; k < K; ++k) {
        const float4 w4 = *(const float4*)&wt[k * 64 + ((cg ^ (k & 15)) << 2)];
#pragma unroll
        for (int i = 0; i < RPT; ++i) {
            const float a = xs[rs + 16 * i][k];
            acc[i][0] += a * w4.x;
            acc[i][1] += a * w4.y;
            acc[i][2] += a * w4.z;
            acc[i][3] += a * w4.w;
        }
    }

#pragma unroll
    for (int i = 0; i < RPT; ++i) {
        const int row = base + rs + 16 * i;
        if (row < N) {
            float4 r4 = make_float4(acc[i][0], acc[i][1], acc[i][2], acc[i][3]);
            if (relu) {
                r4.x = fmaxf(r4.x, 0.f); r4.y = fmaxf(r4.y, 0.f);
                r4.z = fmaxf(r4.z, 0.f); r4.w = fmaxf(r4.w, 0.f);
            }
            *(float4*)(out + (size_t)row * 64 + 4 * cg) = r4;
        }
    }
}

// ---------------------------------------------------------------------------
// Fused GIN conv: out[64-node tile] = act((h + seg_sum(h[slots]))@W.T + b).
// Phase 1: 16 lanes/node gather (4-deep) + h-row add -> xs LDS tile.
// Phase 2: register-tiled GEMM on xs with swizzled wt.
// Reads h only (never its own output buffer) -> safe to write a buffer no
// other block reads (d_out).
// ---------------------------------------------------------------------------
template <int RELU>
__global__ __launch_bounds__(256) void conv_fused(
    const float* __restrict__ h, const unsigned* __restrict__ slots,
    const int* __restrict__ offs, const float* __restrict__ W,
    const float* __restrict__ bias, float* __restrict__ out, int N)
{
    __shared__ float xs[64][65];
    __shared__ float wt[64 * 64];
    const int tid = threadIdx.x;

    for (int idx = tid; idx < 64 * 64; idx += 256) {
        const int j = idx >> 6;
        const int k = idx & 63;
        const int g = (j >> 2) ^ (k & 15);
        wt[k * 64 + (g << 2) + (j & 3)] = W[idx];
    }

    const int base = blockIdx.x * 64;
    const int ns = tid >> 4;          // node slot 0..15
    const int q  = (tid & 15) * 4;    // col offset

#pragma unroll
    for (int p = 0; p < 4; ++p) {
        const int node = base + p * 16 + ns;
        float4 acc = make_float4(0.f, 0.f, 0.f, 0.f);
        if (node < N) {
            acc = *(const float4*)(h + (size_t)node * 64 + q);  // (1+eps)x_i, eps=0
            const int beg = offs[node];
            const int end = offs[node + 1];
            int j = beg;
            for (; j + 4 <= end; j += 4) {
                const int s0 = slots[j],     s1 = slots[j + 1];
                const int s2 = slots[j + 2], s3 = slots[j + 3];
                const float4 v0 = *(const float4*)(h + (size_t)s0 * 64 + q);
                const float4 v1 = *(const float4*)(h + (size_t)s1 * 64 + q);
                const float4 v2 = *(const float4*)(h + (size_t)s2 * 64 + q);
                const float4 v3 = *(const float4*)(h + (size_t)s3 * 64 + q);
                acc.x += (v0.x + v1.x) + (v2.x + v3.x);
                acc.y += (v0.y + v1.y) + (v2.y + v3.y);
                acc.z += (v0.z + v1.z) + (v2.z + v3.z);
                acc.w += (v0.w + v1.w) + (v2.w + v3.w);
            }
            for (; j < end; ++j) {
                const int s0 = slots[j];
                const float4 v0 = *(const float4*)(h + (size_t)s0 * 64 + q);
                acc.x += v0.x; acc.y += v0.y; acc.z += v0.z; acc.w += v0.w;
            }
        }
        float* pp = &xs[p * 16 + ns][q];
        pp[0] = acc.x; pp[1] = acc.y; pp[2] = acc.z; pp[3] = acc.w;
    }
    __syncthreads();

    const int cg = tid & 15;
    const int rs = tid >> 4;

    float acc[4][4];
    const float4 bv = *(const float4*)(bias + 4 * cg);
#pragma unroll
    for (int i = 0; i < 4; ++i) {
        acc[i][0] = bv.x; acc[i][1] = bv.y; acc[i][2] = bv.z; acc[i][3] = bv.w;
    }

#pragma unroll 4
    for (int k = 0; k < 64; ++k) {
        const float4 w4 = *(const float4*)&wt[k * 64 + ((cg ^ (k & 15)) << 2)];
#pragma unroll
        for (int i = 0; i < 4; ++i) {
            const float a = xs[rs + 16 * i][k];
            acc[i][0] += a * w4.x;
            acc[i][1] += a * w4.y;
            acc[i][2] += a * w4.z;
            acc[i][3] += a * w4.w;
        }
    }

#pragma unroll
    for (int i = 0; i < 4; ++i) {
        const int row = base + rs + 16 * i;
        if (row < N) {
            float4 r4 = make_float4(acc[i][0], acc[i][1], acc[i][2], acc[i][3]);
            if (RELU) {
                r4.x = fmaxf(r4.x, 0.f); r4.y = fmaxf(r4.y, 0.f);
                r4.z = fmaxf(r4.z, 0.f); r4.w = fmaxf(r4.w, 0.f);
            }
            *(float4*)(out + (size_t)row * 64 + 4 * cg) = r4;
        }
    }
}

// ---------------------------------------------------------------------------
// CSR build via 2-level counting sort (R5).
// ---------------------------------------------------------------------------
constexpr int CHUNK = 4096;

__global__ __launch_bounds__(256) void p_hist(
    const int* __restrict__ dst, int* __restrict__ counts,
    int E, int NBK, int NC)
{
    __shared__ int cnt[512];
    const int c = blockIdx.x;
    for (int b = threadIdx.x; b < NBK; b += 256) cnt[b] = 0;
    __syncthreads();
    const int beg = c * CHUNK;
    const int end = min(beg + CHUNK, E);
    for (int e = beg + threadIdx.x; e < end; e += 256)
        atomicAdd(&cnt[dst[e] >> 8], 1);
    __syncthreads();
    for (int b = threadIdx.x; b < NBK; b += 256)
        counts[b * NC + c] = cnt[b];
}

__global__ __launch_bounds__(256) void k_blocksum(
    const int* __restrict__ in, int* __restrict__ partial, int n)
{
    __shared__ int s[256];
    const int i = blockIdx.x * 256 + threadIdx.x;
    s[threadIdx.x] = (i < n) ? in[i] : 0;
    __syncthreads();
    for (int off = 128; off > 0; off >>= 1) {
        if (threadIdx.x < off) s[threadIdx.x] += s[threadIdx.x + off];
        __syncthreads();
    }
    if (threadIdx.x == 0) partial[blockIdx.x] = s[0];
}

__global__ __launch_bounds__(1024) void k_scanpartial1024(
    int* __restrict__ partial, int nblk)
{
    __shared__ int s[1024];
    const int t = threadIdx.x;
    s[t] = (t < nblk) ? partial[t] : 0;
    __syncthreads();
    for (int off = 1; off < 1024; off <<= 1) {
        const int v = (t >= off) ? s[t - off] : 0;
        __syncthreads();
        s[t] += v;
        __syncthreads();
    }
    if (t < nblk) partial[t] = (t == 0) ? 0 : s[t - 1];
}

__global__ __launch_bounds__(256) void k_exscan(
    int* __restrict__ data, const int* __restrict__ partial, int n)
{
    __shared__ int s[256];
    const int i = blockIdx.x * 256 + threadIdx.x;
    const int t = threadIdx.x;
    const int v = (i < n) ? data[i] : 0;
    s[t] = v;
    __syncthreads();
    for (int off = 1; off < 256; off <<= 1) {
        const int u = (t >= off) ? s[t - off] : 0;
        __syncthreads();
        s[t] += u;
        __syncthreads();
    }
    if (i < n) data[i] = partial[blockIdx.x] + s[t] - v;   // exclusive
}

__global__ __launch_bounds__(256) void p_scatter(
    const int* __restrict__ src, const int* __restrict__ dst,
    const int* __restrict__ counts, unsigned* __restrict__ slots,
    int E, int NBK, int NC)
{
    __shared__ int cur[512];
    const int c = blockIdx.x;
    for (int b = threadIdx.x; b < NBK; b += 256) cur[b] = counts[b * NC + c];
    __syncthreads();
    const int beg = c * CHUNK;
    const int end = min(beg + CHUNK, E);
    for (int e = beg + threadIdx.x; e < end; e += 256) {
        const int d = dst[e];
        const int pos = atomicAdd(&cur[d >> 8], 1);
        slots[pos] = ((unsigned)(d & 255) << 24) | (unsigned)src[e];
    }
}

__global__ __launch_bounds__(256) void p_bucket(
    unsigned* __restrict__ slots, const int* __restrict__ counts,
    int* __restrict__ offs, unsigned* __restrict__ scratch,
    int E, int N, int NBK, int NC)
{
    __shared__ int cnt[256];
    __shared__ int noff[256];
    __shared__ unsigned outl[8192];
    const int b = blockIdx.x;
    const int t = threadIdx.x;
    const int base = counts[b * NC];
    const int next = (b == NBK - 1) ? E : counts[(b + 1) * NC];
    const int size = next - base;

    cnt[t] = 0;
    __syncthreads();
    for (int i = t; i < size; i += 256)
        atomicAdd(&cnt[slots[base + i] >> 24], 1);
    __syncthreads();

    const int v = cnt[t];
    noff[t] = v;
    __syncthreads();
    for (int off = 1; off < 256; off <<= 1) {
        const int u = (t >= off) ? noff[t - off] : 0;
        __syncthreads();
        noff[t] += u;
        __syncthreads();
    }
    const int ex = noff[t] - v;
    __syncthreads();
    noff[t] = ex;
    cnt[t] = ex;
    __syncthreads();

    const int node = (b << 8) + t;
    if (node <= N) offs[node] = base + noff[t];

    if (size <= 8192) {
        for (int i = t; i < size; i += 256) {
            const unsigned p = slots[base + i];
            const int pos = atomicAdd(&cnt[p >> 24], 1);
            outl[pos] = p & 0x00FFFFFFu;
        }
        __syncthreads();
        for (int i = t; i < size; i += 256) slots[base + i] = outl[i];
    } else {
        for (int i = t; i < size; i += 256) scratch[base + i] = slots[base + i];
        __threadfence();
        __syncthreads();
        for (int i = t; i < size; i += 256) {
            const unsigned p = scratch[base + i];
            const int pos = atomicAdd(&cnt[p >> 24], 1);
            slots[base + pos] = p & 0x00FFFFFFu;
        }
    }
}

// ---------------------------------------------------------------------------
// Standalone gather (conv1): 16 lanes/node, 4-deep load pipeline.
// ---------------------------------------------------------------------------
__global__ __launch_bounds__(256) void gather_sum(
    const float* __restrict__ h, const int* __restrict__ slots,
    const int* __restrict__ offs, float* __restrict__ agg, int N)
{
    const int g = blockIdx.x * 256 + threadIdx.x;
    const int n = g >> 4;
    if (n >= N) return;
    const int q = (g & 15) * 4;
    const int beg = offs[n];
    const int end = offs[n + 1];
    float4 acc = make_float4(0.f, 0.f, 0.f, 0.f);
    int j = beg;
    for (; j + 4 <= end; j += 4) {
        const int s0 = slots[j],     s1 = slots[j + 1];
        const int s2 = slots[j + 2], s3 = slots[j + 3];
        const float4 v0 = *(const float4*)(h + (size_t)s0 * 64 + q);
        const float4 v1 = *(const float4*)(h + (size_t)s1 * 64 + q);
        const float4 v2 = *(const float4*)(h + (size_t)s2 * 64 + q);
        const float4 v3 = *(const float4*)(h + (size_t)s3 * 64 + q);
        acc.x += (v0.x + v1.x) + (v2.x + v3.x);
        acc.y += (v0.y + v1.y) + (v2.y + v3.y);
        acc.z += (v0.z + v1.z) + (v2.z + v3.z);
        acc.w += (v0.w + v1.w) + (v2.w + v3.w);
    }
    for (; j < end; ++j) {
        const int s0 = slots[j];
        const float4 v0 = *(const float4*)(h + (size_t)s0 * 64 + q);
        acc.x += v0.x; acc.y += v0.y; acc.z += v0.z; acc.w += v0.w;
    }
    *(float4*)(agg + (size_t)n * 64 + q) = acc;
}

extern "C" void kernel_launch(void* const* d_in, const int* in_sizes, int n_in,
                              void* d_out, int out_size, void* d_ws, size_t ws_size,
                              hipStream_t stream)
{
    const float* x       = (const float*)d_in[0];
    const int*   ei      = (const int*)  d_in[1];
    const float* W_pre   = (const float*)d_in[2];
    const float* b_pre   = (const float*)d_in[3];
    const float* W_first = (const float*)d_in[4];
    const float* b_first = (const float*)d_in[5];
    const float* W_out   = (const float*)d_in[6];
    const float* b_out   = (const float*)d_in[7];

    const int N = in_sizes[0] / 128;
    const int E = in_sizes[1] / 2;
    const int* src = ei;
    const int* dst = ei + E;

    const int NBK = (N >> 8) + 1;
    const int NC  = (E + CHUNK - 1) / CHUNK;
    const int nscan = NBK * NC;
    const int nsblk = (nscan + 255) / 256;

    // Workspace layout (~33 MB):
    float*    h      = (float*)d_ws;                      // [N,64]
    unsigned* slots  = (unsigned*)(h + (size_t)N * 64);   // [E]
    int*      counts = (int*)(slots + E);                 // [NBK*NC]
    int*      partial= counts + nscan;                    // [<=1024]
    int*      offs   = partial + 1024;                    // [N+1]

    float* agg = (float*)d_out;   // agg for conv1 only
    float* out = (float*)d_out;

    const int node16_blocks    = (N * 16 + 255) / 256;
    const int gemm_pre_blocks  = (N + 31) / 32;
    const int gemm_conv_blocks = (N + 63) / 64;

    // --- CSR build (d_out free as overflow scratch here) ---
    p_hist<<<NC, 256, 0, stream>>>(dst, counts, E, NBK, NC);
    k_blocksum<<<nsblk, 256, 0, stream>>>(counts, partial, nscan);
    k_scanpartial1024<<<1, 1024, 0, stream>>>(partial, nsblk);
    k_exscan<<<nsblk, 256, 0, stream>>>(counts, partial, nscan);
    p_scatter<<<NC, 256, 0, stream>>>(src, dst, counts, slots, E, NBK, NC);
    p_bucket<<<NBK, 256, 0, stream>>>(slots, counts, offs, (unsigned*)d_out,
                                      E, N, NBK, NC);

    // --- 1. h = x @ W_pre.T + b_pre ---
    gemm_nodes<128, 2><<<gemm_pre_blocks, 256, 0, stream>>>(
        x, nullptr, W_pre, b_pre, h, N, 0);

    // --- 2. conv1: agg = seg_sum(h); h = relu((h+agg)@W_first.T + b_first) ---
    gather_sum<<<node16_blocks, 256, 0, stream>>>(h, (const int*)slots, offs, agg, N);
    gemm_nodes<64, 4><<<gemm_conv_blocks, 256, 0, stream>>>(
        h, agg, W_first, b_first, h, N, 1);

    // --- 3. conv2 fused: out = (h + seg_sum(h))@W_out.T + b_out ---
    conv_fused<0><<<gemm_conv_blocks, 256, 0, stream>>>(
        h, slots, offs, W_out, b_out, out, N);
}

// Round 7
// 209.731 us; speedup vs baseline: 15.3147x; 1.1584x over previous
//
#include <hip/hip_runtime.h>

// GIN forward: h = x@W_pre.T + b_pre
//              h = relu((h + seg_sum(h[src]->dst)) @ W_first.T + b_first)
//              out = (h + seg_sum(h[src]->dst)) @ W_out.T + b_out
// N=100000, E=1600000, IN=128, D=64.
//
// R7: gathers are L3-latency-bound on ~180MB of compulsory cross-XCD fetch
// (h doesn't fit per-XCD L2). (1) GEMM epilogues also emit a bf16 mirror h16;
// both gathers read h16 -> half the random-fetch bytes. Self/GEMM paths stay
// f32. (2) conv_fused re-tiled to 32 nodes/block (24.7KB LDS -> 6 blocks/CU).

__device__ inline unsigned short f2bf(float f) {
    unsigned b = __float_as_uint(f);
    return (unsigned short)((b + 0x7FFF + ((b >> 16) & 1)) >> 16);
}
__device__ inline float bf2f(unsigned short u) {
    return __uint_as_float((unsigned)u << 16);
}
__device__ inline float4 bf4_to_f4(ushort4 u) {
    return make_float4(bf2f(u.x), bf2f(u.y), bf2f(u.z), bf2f(u.w));
}

// ---------------------------------------------------------------------------
// Node GEMM: out[N,64] = act((A [+ A2])[N,K] @ W[64,K]^T + bias)
// wt swizzle: W[j][k] at wt[k*64 + (((j>>2)^(k&15))<<2) + (j&3)]; read is a
// conflict-free aligned ds_read_b128. Unroll capped at 4 (VGPR budget).
// Optionally also writes bf16 mirror out16.
// ---------------------------------------------------------------------------
template <int K, int RPT>
__global__ __launch_bounds__(256) void gemm_nodes(
    const float* __restrict__ A, const float* __restrict__ A2,
    const float* __restrict__ W, const float* __restrict__ bias,
    float* __restrict__ out, unsigned short* __restrict__ out16,
    int N, int relu)
{
    constexpr int ROWS = 16 * RPT;
    __shared__ float xs[ROWS][K + 1];
    __shared__ float wt[K * 64];

    const int tid = threadIdx.x;

    for (int idx = tid; idx < 64 * K; idx += 256) {
        const int j = idx >> (K == 128 ? 7 : 6);
        const int k = idx & (K - 1);
        const int g = (j >> 2) ^ (k & 15);
        wt[k * 64 + (g << 2) + (j & 3)] = W[idx];
    }

    const int base = blockIdx.x * ROWS;
    constexpr int Q = K / 4;
    for (int i4 = tid; i4 < ROWS * Q; i4 += 256) {
        const int r = i4 / Q;
        const int q = i4 - r * Q;
        int row = base + r;
        if (row > N - 1) row = N - 1;
        float4 v = *(const float4*)(A + (size_t)row * K + q * 4);
        if (A2) {
            const float4 vb = *(const float4*)(A2 + (size_t)row * K + q * 4);
            v.x += vb.x; v.y += vb.y; v.z += vb.z; v.w += vb.w;
        }
        float* p = &xs[r][q * 4];
        p[0] = v.x; p[1] = v.y; p[2] = v.z; p[3] = v.w;
    }
    __syncthreads();

    const int cg = tid & 15;
    const int rs = tid >> 4;

    float acc[RPT][4];
    const float4 bv = *(const float4*)(bias + 4 * cg);
#pragma unroll
    for (int i = 0; i < RPT; ++i) {
        acc[i][0] = bv.x; acc[i][1] = bv.y; acc[i][2] = bv.z; acc[i][3] = bv.w;
    }

#pragma unroll 4
    for (int k = 0; k < K; ++k) {
        const float4 w4 = *(const float4*)&wt[k * 64 + ((cg ^ (k & 15)) << 2)];
#pragma unroll
        for (int i = 0; i < RPT; ++i) {
            const float a = xs[rs + 16 * i][k];
            acc[i][0] += a * w4.x;
            acc[i][1] += a * w4.y;
            acc[i][2] += a * w4.z;
            acc[i][3] += a * w4.w;
        }
    }

#pragma unroll
    for (int i = 0; i < RPT; ++i) {
        const int row = base + rs + 16 * i;
        if (row < N) {
            float4 r4 = make_float4(acc[i][0], acc[i][1], acc[i][2], acc[i][3]);
            if (relu) {
                r4.x = fmaxf(r4.x, 0.f); r4.y = fmaxf(r4.y, 0.f);
                r4.z = fmaxf(r4.z, 0.f); r4.w = fmaxf(r4.w, 0.f);
            }
            *(float4*)(out + (size_t)row * 64 + 4 * cg) = r4;
            if (out16) {
                ushort4 u = make_ushort4(f2bf(r4.x), f2bf(r4.y),
                                         f2bf(r4.z), f2bf(r4.w));
                *(ushort4*)(out16 + (size_t)row * 64 + 4 * cg) = u;
            }
        }
    }
}

// ---------------------------------------------------------------------------
// Fused GIN conv2: out[32-node tile] = (h + seg_sum(h16[slots]))@W.T + b.
// 24.7KB LDS -> 6 blocks/CU for latency hiding in the gather phase.
// ---------------------------------------------------------------------------
__global__ __launch_bounds__(256) void conv_fused(
    const float* __restrict__ h, const unsigned short* __restrict__ h16,
    const unsigned* __restrict__ slots, const int* __restrict__ offs,
    const float* __restrict__ W, const float* __restrict__ bias,
    float* __restrict__ out, int N)
{
    __shared__ float xs[32][65];
    __shared__ float wt[64 * 64];
    const int tid = threadIdx.x;

    for (int idx = tid; idx < 64 * 64; idx += 256) {
        const int j = idx >> 6;
        const int k = idx & 63;
        const int g = (j >> 2) ^ (k & 15);
        wt[k * 64 + (g << 2) + (j & 3)] = W[idx];
    }

    const int base = blockIdx.x * 32;
    const int ns = tid >> 4;          // node slot 0..15
    const int q  = (tid & 15) * 4;    // col offset

#pragma unroll
    for (int p = 0; p < 2; ++p) {
        const int node = base + p * 16 + ns;
        float4 acc = make_float4(0.f, 0.f, 0.f, 0.f);
        if (node < N) {
            acc = *(const float4*)(h + (size_t)node * 64 + q);  // (1+eps)x_i
            const int beg = offs[node];
            const int end = offs[node + 1];
            int j = beg;
            for (; j + 4 <= end; j += 4) {
                const int s0 = slots[j],     s1 = slots[j + 1];
                const int s2 = slots[j + 2], s3 = slots[j + 3];
                const ushort4 u0 = *(const ushort4*)(h16 + (size_t)s0 * 64 + q);
                const ushort4 u1 = *(const ushort4*)(h16 + (size_t)s1 * 64 + q);
                const ushort4 u2 = *(const ushort4*)(h16 + (size_t)s2 * 64 + q);
                const ushort4 u3 = *(const ushort4*)(h16 + (size_t)s3 * 64 + q);
                const float4 v0 = bf4_to_f4(u0), v1 = bf4_to_f4(u1);
                const float4 v2 = bf4_to_f4(u2), v3 = bf4_to_f4(u3);
                acc.x += (v0.x + v1.x) + (v2.x + v3.x);
                acc.y += (v0.y + v1.y) + (v2.y + v3.y);
                acc.z += (v0.z + v1.z) + (v2.z + v3.z);
                acc.w += (v0.w + v1.w) + (v2.w + v3.w);
            }
            for (; j < end; ++j) {
                const float4 v0 = bf4_to_f4(
                    *(const ushort4*)(h16 + (size_t)slots[j] * 64 + q));
                acc.x += v0.x; acc.y += v0.y; acc.z += v0.z; acc.w += v0.w;
            }
        }
        float* pp = &xs[p * 16 + ns][q];
        pp[0] = acc.x; pp[1] = acc.y; pp[2] = acc.z; pp[3] = acc.w;
    }
    __syncthreads();

    const int cg = tid & 15;
    const int rs = tid >> 4;

    float acc[2][4];
    const float4 bv = *(const float4*)(bias + 4 * cg);
#pragma unroll
    for (int i = 0; i < 2; ++i) {
        acc[i][0] = bv.x; acc[i][1] = bv.y; acc[i][2] = bv.z; acc[i][3] = bv.w;
    }

#pragma unroll 4
    for (int k = 0; k < 64; ++k) {
        const float4 w4 = *(const float4*)&wt[k * 64 + ((cg ^ (k & 15)) << 2)];
#pragma unroll
        for (int i = 0; i < 2; ++i) {
            const float a = xs[rs + 16 * i][k];
            acc[i][0] += a * w4.x;
            acc[i][1] += a * w4.y;
            acc[i][2] += a * w4.z;
            acc[i][3] += a * w4.w;
        }
    }

#pragma unroll
    for (int i = 0; i < 2; ++i) {
        const int row = base + rs + 16 * i;
        if (row < N) {
            *(float4*)(out + (size_t)row * 64 + 4 * cg) =
                make_float4(acc[i][0], acc[i][1], acc[i][2], acc[i][3]);
        }
    }
}

// ---------------------------------------------------------------------------
// CSR build via 2-level counting sort (R5).
// ---------------------------------------------------------------------------
constexpr int CHUNK = 4096;

__global__ __launch_bounds__(256) void p_hist(
    const int* __restrict__ dst, int* __restrict__ counts,
    int E, int NBK, int NC)
{
    __shared__ int cnt[512];
    const int c = blockIdx.x;
    for (int b = threadIdx.x; b < NBK; b += 256) cnt[b] = 0;
    __syncthreads();
    const int beg = c * CHUNK;
    const int end = min(beg + CHUNK, E);
    for (int e = beg + threadIdx.x; e < end; e += 256)
        atomicAdd(&cnt[dst[e] >> 8], 1);
    __syncthreads();
    for (int b = threadIdx.x; b < NBK; b += 256)
        counts[b * NC + c] = cnt[b];
}

__global__ __launch_bounds__(256) void k_blocksum(
    const int* __restrict__ in, int* __restrict__ partial, int n)
{
    __shared__ int s[256];
    const int i = blockIdx.x * 256 + threadIdx.x;
    s[threadIdx.x] = (i < n) ? in[i] : 0;
    __syncthreads();
    for (int off = 128; off > 0; off >>= 1) {
        if (threadIdx.x < off) s[threadIdx.x] += s[threadIdx.x + off];
        __syncthreads();
    }
    if (threadIdx.x == 0) partial[blockIdx.x] = s[0];
}

__global__ __launch_bounds__(1024) void k_scanpartial1024(
    int* __restrict__ partial, int nblk)
{
    __shared__ int s[1024];
    const int t = threadIdx.x;
    s[t] = (t < nblk) ? partial[t] : 0;
    __syncthreads();
    for (int off = 1; off < 1024; off <<= 1) {
        const int v = (t >= off) ? s[t - off] : 0;
        __syncthreads();
        s[t] += v;
        __syncthreads();
    }
    if (t < nblk) partial[t] = (t == 0) ? 0 : s[t - 1];
}

__global__ __launch_bounds__(256) void k_exscan(
    int* __restrict__ data, const int* __restrict__ partial, int n)
{
    __shared__ int s[256];
    const int i = blockIdx.x * 256 + threadIdx.x;
    const int t = threadIdx.x;
    const int v = (i < n) ? data[i] : 0;
    s[t] = v;
    __syncthreads();
    for (int off = 1; off < 256; off <<= 1) {
        const int u = (t >= off) ? s[t - off] : 0;
        __syncthreads();
        s[t] += u;
        __syncthreads();
    }
    if (i < n) data[i] = partial[blockIdx.x] + s[t] - v;   // exclusive
}

__global__ __launch_bounds__(256) void p_scatter(
    const int* __restrict__ src, const int* __restrict__ dst,
    const int* __restrict__ counts, unsigned* __restrict__ slots,
    int E, int NBK, int NC)
{
    __shared__ int cur[512];
    const int c = blockIdx.x;
    for (int b = threadIdx.x; b < NBK; b += 256) cur[b] = counts[b * NC + c];
    __syncthreads();
    const int beg = c * CHUNK;
    const int end = min(beg + CHUNK, E);
    for (int e = beg + threadIdx.x; e < end; e += 256) {
        const int d = dst[e];
        const int pos = atomicAdd(&cur[d >> 8], 1);
        slots[pos] = ((unsigned)(d & 255) << 24) | (unsigned)src[e];
    }
}

__global__ __launch_bounds__(256) void p_bucket(
    unsigned* __restrict__ slots, const int* __restrict__ counts,
    int* __restrict__ offs, unsigned* __restrict__ scratch,
    int E, int N, int NBK, int NC)
{
    __shared__ int cnt[256];
    __shared__ int noff[256];
    __shared__ unsigned outl[8192];
    const int b = blockIdx.x;
    const int t = threadIdx.x;
    const int base = counts[b * NC];
    const int next = (b == NBK - 1) ? E : counts[(b + 1) * NC];
    const int size = next - base;

    cnt[t] = 0;
    __syncthreads();
    for (int i = t; i < size; i += 256)
        atomicAdd(&cnt[slots[base + i] >> 24], 1);
    __syncthreads();

    const int v = cnt[t];
    noff[t] = v;
    __syncthreads();
    for (int off = 1; off < 256; off <<= 1) {
        const int u = (t >= off) ? noff[t - off] : 0;
        __syncthreads();
        noff[t] += u;
        __syncthreads();
    }
    const int ex = noff[t] - v;
    __syncthreads();
    noff[t] = ex;
    cnt[t] = ex;
    __syncthreads();

    const int node = (b << 8) + t;
    if (node <= N) offs[node] = base + noff[t];

    if (size <= 8192) {
        for (int i = t; i < size; i += 256) {
            const unsigned p = slots[base + i];
            const int pos = atomicAdd(&cnt[p >> 24], 1);
            outl[pos] = p & 0x00FFFFFFu;
        }
        __syncthreads();
        for (int i = t; i < size; i += 256) slots[base + i] = outl[i];
    } else {
        for (int i = t; i < size; i += 256) scratch[base + i] = slots[base + i];
        __threadfence();
        __syncthreads();
        for (int i = t; i < size; i += 256) {
            const unsigned p = scratch[base + i];
            const int pos = atomicAdd(&cnt[p >> 24], 1);
            slots[base + pos] = p & 0x00FFFFFFu;
        }
    }
}

// ---------------------------------------------------------------------------
// Standalone gather (conv1): 16 lanes/node, 4-deep, reads bf16 mirror.
// ---------------------------------------------------------------------------
__global__ __launch_bounds__(256) void gather_sum(
    const unsigned short* __restrict__ h16, const int* __restrict__ slots,
    const int* __restrict__ offs, float* __restrict__ agg, int N)
{
    const int g = blockIdx.x * 256 + threadIdx.x;
    const int n = g >> 4;
    if (n >= N) return;
    const int q = (g & 15) * 4;
    const int beg = offs[n];
    const int end = offs[n + 1];
    float4 acc = make_float4(0.f, 0.f, 0.f, 0.f);
    int j = beg;
    for (; j + 4 <= end; j += 4) {
        const int s0 = slots[j],     s1 = slots[j + 1];
        const int s2 = slots[j + 2], s3 = slots[j + 3];
        const ushort4 u0 = *(const ushort4*)(h16 + (size_t)s0 * 64 + q);
        const ushort4 u1 = *(const ushort4*)(h16 + (size_t)s1 * 64 + q);
        const ushort4 u2 = *(const ushort4*)(h16 + (size_t)s2 * 64 + q);
        const ushort4 u3 = *(const ushort4*)(h16 + (size_t)s3 * 64 + q);
        const float4 v0 = bf4_to_f4(u0), v1 = bf4_to_f4(u1);
        const float4 v2 = bf4_to_f4(u2), v3 = bf4_to_f4(u3);
        acc.x += (v0.x + v1.x) + (v2.x + v3.x);
        acc.y += (v0.y + v1.y) + (v2.y + v3.y);
        acc.z += (v0.z + v1.z) + (v2.z + v3.z);
        acc.w += (v0.w + v1.w) + (v2.w + v3.w);
    }
    for (; j < end; ++j) {
        const float4 v0 = bf4_to_f4(
            *(const ushort4*)(h16 + (size_t)slots[j] * 64 + q));
        acc.x += v0.x; acc.y += v0.y; acc.z += v0.z; acc.w += v0.w;
    }
    *(float4*)(agg + (size_t)n * 64 + q) = acc;
}

extern "C" void kernel_launch(void* const* d_in, const int* in_sizes, int n_in,
                              void* d_out, int out_size, void* d_ws, size_t ws_size,
                              hipStream_t stream)
{
    const float* x       = (const float*)d_in[0];
    const int*   ei      = (const int*)  d_in[1];
    const float* W_pre   = (const float*)d_in[2];
    const float* b_pre   = (const float*)d_in[3];
    const float* W_first = (const float*)d_in[4];
    const float* b_first = (const float*)d_in[5];
    const float* W_out   = (const float*)d_in[6];
    const float* b_out   = (const float*)d_in[7];

    const int N = in_sizes[0] / 128;
    const int E = in_sizes[1] / 2;
    const int* src = ei;
    const int* dst = ei + E;

    const int NBK = (N >> 8) + 1;
    const int NC  = (E + CHUNK - 1) / CHUNK;
    const int nscan = NBK * NC;
    const int nsblk = (nscan + 255) / 256;

    // Workspace layout (~46 MB):
    float*          h      = (float*)d_ws;                       // [N,64] f32
    unsigned short* h16    = (unsigned short*)(h + (size_t)N * 64); // [N,64] bf16
    unsigned*       slots  = (unsigned*)(h16 + (size_t)N * 64);  // [E]
    int*            counts = (int*)(slots + E);                  // [NBK*NC]
    int*            partial= counts + nscan;                     // [<=1024]
    int*            offs   = partial + 1024;                     // [N+1]

    float* agg = (float*)d_out;   // agg for conv1 only
    float* out = (float*)d_out;

    const int node16_blocks    = (N * 16 + 255) / 256;
    const int gemm_pre_blocks  = (N + 31) / 32;
    const int gemm_conv_blocks = (N + 63) / 64;
    const int conv2_blocks     = (N + 31) / 32;

    // --- CSR build (d_out free as overflow scratch here) ---
    p_hist<<<NC, 256, 0, stream>>>(dst, counts, E, NBK, NC);
    k_blocksum<<<nsblk, 256, 0, stream>>>(counts, partial, nscan);
    k_scanpartial1024<<<1, 1024, 0, stream>>>(partial, nsblk);
    k_exscan<<<nsblk, 256, 0, stream>>>(counts, partial, nscan);
    p_scatter<<<NC, 256, 0, stream>>>(src, dst, counts, slots, E, NBK, NC);
    p_bucket<<<NBK, 256, 0, stream>>>(slots, counts, offs, (unsigned*)d_out,
                                      E, N, NBK, NC);

    // --- 1. h = x @ W_pre.T + b_pre  (+ bf16 mirror) ---
    gemm_nodes<128, 2><<<gemm_pre_blocks, 256, 0, stream>>>(
        x, nullptr, W_pre, b_pre, h, h16, N, 0);

    // --- 2. conv1: agg = seg_sum(h16); h = relu((h+agg)@W_first.T + b) ---
    gather_sum<<<node16_blocks, 256, 0, stream>>>(
        h16, (const int*)slots, offs, agg, N);
    gemm_nodes<64, 4><<<gemm_conv_blocks, 256, 0, stream>>>(
        h, agg, W_first, b_first, h, h16, N, 1);

    // --- 3. conv2 fused: out = (h + seg_sum(h16))@W_out.T + b_out ---
    conv_fused<<<conv2_blocks, 256, 0, stream>>>(
        h, h16, slots, offs, W_out, b_out, out, N);
}

// Round 8
// 167.183 us; speedup vs baseline: 19.2123x; 1.2545x over previous
//
#include <hip/hip_runtime.h>

// GIN forward: h = x@W_pre.T + b_pre
//              h = relu((h + seg_sum(h[src]->dst)) @ W_first.T + b_first)
//              out = (h + seg_sum(h[src]->dst)) @ W_out.T + b_out
// N=100000, E=1600000, IN=128, D=64.
//
// R8: all GEMMs moved to bf16 MFMA (16x16x32). R7 showed the VALU pre-GEMM at
// 61.7us (VALUBusy 55%, FMA floor 10.4us) - ~100us total GEMM cost. MFMA makes
// GEMM staging-bound (~25us total). Inputs bf16-quantized in LDS staging.
// Gathers: 8 lanes x 16B per row. CSR CHUNK 8192.

using bf16x8 = __attribute__((ext_vector_type(8))) short;
using f32x4  = __attribute__((ext_vector_type(4))) float;

__device__ inline unsigned short f2bf(float f) {
    unsigned b = __float_as_uint(f);
    return (unsigned short)((b + 0x7FFF + ((b >> 16) & 1)) >> 16);
}
__device__ inline float bf2f_lo(unsigned u) { return __uint_as_float(u << 16); }
__device__ inline float bf2f_hi(unsigned u) { return __uint_as_float(u & 0xFFFF0000u); }
__device__ inline unsigned packbf(float lo, float hi) {
    return (unsigned)f2bf(lo) | ((unsigned)f2bf(hi) << 16);
}
__device__ inline void acc8(float* a, const uint4 u) {
    a[0] += bf2f_lo(u.x); a[1] += bf2f_hi(u.x);
    a[2] += bf2f_lo(u.y); a[3] += bf2f_hi(u.y);
    a[4] += bf2f_lo(u.z); a[5] += bf2f_hi(u.z);
    a[6] += bf2f_lo(u.w); a[7] += bf2f_hi(u.w);
}

// ---------------------------------------------------------------------------
// MFMA node GEMM: out[N,64] = act((A [+ A2])[N,K] @ W[64,K]^T + bias).
// Block: 256 thr = 4 waves, 64 rows x 64 cols. A,W staged as bf16 row-major
// tiles; lane&15 = row(A)/col(W-row), 8 consecutive k per lane per frag.
// C/D: col=lane&15, row=(lane>>4)*4+reg (m89-verified, dtype-independent).
// ---------------------------------------------------------------------------
template <int K, int RELU, int W16>
__global__ __launch_bounds__(256) void gemm_mfma(
    const float* __restrict__ A, const float* __restrict__ A2,
    const float* __restrict__ W, const float* __restrict__ bias,
    float* __restrict__ out, unsigned short* __restrict__ out16, int N)
{
    constexpr int SP = K + 16;                    // ushort stride; x2B is 16B-aligned
    __shared__ unsigned short xs[64][SP];
    __shared__ unsigned short ws[64][SP];
    const int tid = threadIdx.x;
    const int base = blockIdx.x * 64;
    constexpr int Q = K / 4;                      // float4 per row
    constexpr int WQ = 64 * Q;

    for (int i = tid; i < WQ; i += 256) {         // stage W -> bf16
        const int r = i / Q, q = i - r * Q;
        const float4 v = *(const float4*)(W + r * K + q * 4);
        *(ushort4*)&ws[r][q * 4] =
            make_ushort4(f2bf(v.x), f2bf(v.y), f2bf(v.z), f2bf(v.w));
    }
    for (int i = tid; i < WQ; i += 256) {         // stage A (+A2) -> bf16
        const int r = i / Q, q = i - r * Q;
        int row = base + r; if (row > N - 1) row = N - 1;
        float4 v = *(const float4*)(A + (size_t)row * K + q * 4);
        if (A2) {
            const float4 w2 = *(const float4*)(A2 + (size_t)row * K + q * 4);
            v.x += w2.x; v.y += w2.y; v.z += w2.z; v.w += w2.w;
        }
        *(ushort4*)&xs[r][q * 4] =
            make_ushort4(f2bf(v.x), f2bf(v.y), f2bf(v.z), f2bf(v.w));
    }
    __syncthreads();

    const int w  = tid >> 6;       // wave -> 16-row stripe
    const int l  = tid & 63;
    const int lr = l & 15;         // frag row (A) / col (B)
    const int lg = l >> 4;         // k-group

    f32x4 acc[4];
#pragma unroll
    for (int nb = 0; nb < 4; ++nb) {
        const float bv = bias[nb * 16 + lr];
        acc[nb] = (f32x4){bv, bv, bv, bv};
    }

#pragma unroll
    for (int kb = 0; kb < K / 32; ++kb) {
        const bf16x8 a = *(const bf16x8*)&xs[w * 16 + lr][kb * 32 + lg * 8];
#pragma unroll
        for (int nb = 0; nb < 4; ++nb) {
            const bf16x8 b = *(const bf16x8*)&ws[nb * 16 + lr][kb * 32 + lg * 8];
            acc[nb] = __builtin_amdgcn_mfma_f32_16x16x32_bf16(a, b, acc[nb], 0, 0, 0);
        }
    }

#pragma unroll
    for (int nb = 0; nb < 4; ++nb) {
#pragma unroll
        for (int r = 0; r < 4; ++r) {
            const int row = base + w * 16 + lg * 4 + r;
            if (row < N) {
                float v = acc[nb][r];
                if (RELU) v = fmaxf(v, 0.f);
                out[(size_t)row * 64 + nb * 16 + lr] = v;
                if (W16) out16[(size_t)row * 64 + nb * 16 + lr] = f2bf(v);
            }
        }
    }
}

// ---------------------------------------------------------------------------
// Fused conv2: out = (h + seg_sum(h16[slots])) @ W.T + b. Gather phase: 8
// lanes/node x uint4 (16B) 4-deep; result tile staged bf16; MFMA phase K=64.
// ---------------------------------------------------------------------------
__global__ __launch_bounds__(256) void conv2_fused(
    const float* __restrict__ h, const unsigned short* __restrict__ h16,
    const unsigned* __restrict__ slots, const int* __restrict__ offs,
    const float* __restrict__ W, const float* __restrict__ bias,
    float* __restrict__ out, int N)
{
    constexpr int SP = 80;
    __shared__ unsigned short xs[64][SP];
    __shared__ unsigned short ws[64][SP];
    const int tid = threadIdx.x;
    const int base = blockIdx.x * 64;

    for (int i = tid; i < 64 * 16; i += 256) {    // stage W -> bf16
        const int r = i >> 4, q = i & 15;
        const float4 v = *(const float4*)(W + r * 64 + q * 4);
        *(ushort4*)&ws[r][q * 4] =
            make_ushort4(f2bf(v.x), f2bf(v.y), f2bf(v.z), f2bf(v.w));
    }

    const int nloc = tid >> 3;                    // 0..31
    const int c    = (tid & 7) * 8;               // col offset (elems)
#pragma unroll
    for (int p = 0; p < 2; ++p) {
        const int node = base + p * 32 + nloc;
        float a[8] = {0.f, 0.f, 0.f, 0.f, 0.f, 0.f, 0.f, 0.f};
        if (node < N) {
            const float4 s0 = *(const float4*)(h + (size_t)node * 64 + c);
            const float4 s1 = *(const float4*)(h + (size_t)node * 64 + c + 4);
            a[0] = s0.x; a[1] = s0.y; a[2] = s0.z; a[3] = s0.w;
            a[4] = s1.x; a[5] = s1.y; a[6] = s1.z; a[7] = s1.w;
            const int beg = offs[node], end = offs[node + 1];
            int j = beg;
            for (; j + 4 <= end; j += 4) {
                const unsigned s0i = slots[j],     s1i = slots[j + 1];
                const unsigned s2i = slots[j + 2], s3i = slots[j + 3];
                const uint4 u0 = *(const uint4*)(h16 + (size_t)s0i * 64 + c);
                const uint4 u1 = *(const uint4*)(h16 + (size_t)s1i * 64 + c);
                const uint4 u2 = *(const uint4*)(h16 + (size_t)s2i * 64 + c);
                const uint4 u3 = *(const uint4*)(h16 + (size_t)s3i * 64 + c);
                acc8(a, u0); acc8(a, u1); acc8(a, u2); acc8(a, u3);
            }
            for (; j < end; ++j) {
                const uint4 u0 = *(const uint4*)(h16 + (size_t)slots[j] * 64 + c);
                acc8(a, u0);
            }
        }
        const uint4 uu = make_uint4(packbf(a[0], a[1]), packbf(a[2], a[3]),
                                    packbf(a[4], a[5]), packbf(a[6], a[7]));
        *(uint4*)&xs[p * 32 + nloc][c] = uu;
    }
    __syncthreads();

    const int w  = tid >> 6;
    const int l  = tid & 63;
    const int lr = l & 15;
    const int lg = l >> 4;

    f32x4 acc[4];
#pragma unroll
    for (int nb = 0; nb < 4; ++nb) {
        const float bv = bias[nb * 16 + lr];
        acc[nb] = (f32x4){bv, bv, bv, bv};
    }
#pragma unroll
    for (int kb = 0; kb < 2; ++kb) {
        const bf16x8 a = *(const bf16x8*)&xs[w * 16 + lr][kb * 32 + lg * 8];
#pragma unroll
        for (int nb = 0; nb < 4; ++nb) {
            const bf16x8 b = *(const bf16x8*)&ws[nb * 16 + lr][kb * 32 + lg * 8];
            acc[nb] = __builtin_amdgcn_mfma_f32_16x16x32_bf16(a, b, acc[nb], 0, 0, 0);
        }
    }
#pragma unroll
    for (int nb = 0; nb < 4; ++nb) {
#pragma unroll
        for (int r = 0; r < 4; ++r) {
            const int row = base + w * 16 + lg * 4 + r;
            if (row < N)
                out[(size_t)row * 64 + nb * 16 + lr] = acc[nb][r];
        }
    }
}

// ---------------------------------------------------------------------------
// CSR build via 2-level counting sort (R5; CHUNK 8192).
// ---------------------------------------------------------------------------
constexpr int CHUNK = 8192;

__global__ __launch_bounds__(256) void p_hist(
    const int* __restrict__ dst, int* __restrict__ counts,
    int E, int NBK, int NC)
{
    __shared__ int cnt[512];
    const int c = blockIdx.x;
    for (int b = threadIdx.x; b < NBK; b += 256) cnt[b] = 0;
    __syncthreads();
    const int beg = c * CHUNK;
    const int end = min(beg + CHUNK, E);
    for (int e = beg + threadIdx.x; e < end; e += 256)
        atomicAdd(&cnt[dst[e] >> 8], 1);
    __syncthreads();
    for (int b = threadIdx.x; b < NBK; b += 256)
        counts[b * NC + c] = cnt[b];
}

__global__ __launch_bounds__(256) void k_blocksum(
    const int* __restrict__ in, int* __restrict__ partial, int n)
{
    __shared__ int s[256];
    const int i = blockIdx.x * 256 + threadIdx.x;
    s[threadIdx.x] = (i < n) ? in[i] : 0;
    __syncthreads();
    for (int off = 128; off > 0; off >>= 1) {
        if (threadIdx.x < off) s[threadIdx.x] += s[threadIdx.x + off];
        __syncthreads();
    }
    if (threadIdx.x == 0) partial[blockIdx.x] = s[0];
}

__global__ __launch_bounds__(1024) void k_scanpartial1024(
    int* __restrict__ partial, int nblk)
{
    __shared__ int s[1024];
    const int t = threadIdx.x;
    s[t] = (t < nblk) ? partial[t] : 0;
    __syncthreads();
    for (int off = 1; off < 1024; off <<= 1) {
        const int v = (t >= off) ? s[t - off] : 0;
        __syncthreads();
        s[t] += v;
        __syncthreads();
    }
    if (t < nblk) partial[t] = (t == 0) ? 0 : s[t - 1];
}

__global__ __launch_bounds__(256) void k_exscan(
    int* __restrict__ data, const int* __restrict__ partial, int n)
{
    __shared__ int s[256];
    const int i = blockIdx.x * 256 + threadIdx.x;
    const int t = threadIdx.x;
    const int v = (i < n) ? data[i] : 0;
    s[t] = v;
    __syncthreads();
    for (int off = 1; off < 256; off <<= 1) {
        const int u = (t >= off) ? s[t - off] : 0;
        __syncthreads();
        s[t] += u;
        __syncthreads();
    }
    if (i < n) data[i] = partial[blockIdx.x] + s[t] - v;   // exclusive
}

__global__ __launch_bounds__(256) void p_scatter(
    const int* __restrict__ src, const int* __restrict__ dst,
    const int* __restrict__ counts, unsigned* __restrict__ slots,
    int E, int NBK, int NC)
{
    __shared__ int cur[512];
    const int c = blockIdx.x;
    for (int b = threadIdx.x; b < NBK; b += 256) cur[b] = counts[b * NC + c];
    __syncthreads();
    const int beg = c * CHUNK;
    const int end = min(beg + CHUNK, E);
    for (int e = beg + threadIdx.x; e < end; e += 256) {
        const int d = dst[e];
        const int pos = atomicAdd(&cur[d >> 8], 1);
        slots[pos] = ((unsigned)(d & 255) << 24) | (unsigned)src[e];
    }
}

__global__ __launch_bounds__(256) void p_bucket(
    unsigned* __restrict__ slots, const int* __restrict__ counts,
    int* __restrict__ offs, unsigned* __restrict__ scratch,
    int E, int N, int NBK, int NC)
{
    __shared__ int cnt[256];
    __shared__ int noff[256];
    __shared__ unsigned outl[8192];
    const int b = blockIdx.x;
    const int t = threadIdx.x;
    const int base = counts[b * NC];
    const int next = (b == NBK - 1) ? E : counts[(b + 1) * NC];
    const int size = next - base;

    cnt[t] = 0;
    __syncthreads();
    for (int i = t; i < size; i += 256)
        atomicAdd(&cnt[slots[base + i] >> 24], 1);
    __syncthreads();

    const int v = cnt[t];
    noff[t] = v;
    __syncthreads();
    for (int off = 1; off < 256; off <<= 1) {
        const int u = (t >= off) ? noff[t - off] : 0;
        __syncthreads();
        noff[t] += u;
        __syncthreads();
    }
    const int ex = noff[t] - v;
    __syncthreads();
    noff[t] = ex;
    cnt[t] = ex;
    __syncthreads();

    const int node = (b << 8) + t;
    if (node <= N) offs[node] = base + noff[t];

    if (size <= 8192) {
        for (int i = t; i < size; i += 256) {
            const unsigned p = slots[base + i];
            const int pos = atomicAdd(&cnt[p >> 24], 1);
            outl[pos] = p & 0x00FFFFFFu;
        }
        __syncthreads();
        for (int i = t; i < size; i += 256) slots[base + i] = outl[i];
    } else {
        for (int i = t; i < size; i += 256) scratch[base + i] = slots[base + i];
        __threadfence();
        __syncthreads();
        for (int i = t; i < size; i += 256) {
            const unsigned p = scratch[base + i];
            const int pos = atomicAdd(&cnt[p >> 24], 1);
            slots[base + pos] = p & 0x00FFFFFFu;
        }
    }
}

// ---------------------------------------------------------------------------
// Standalone gather (conv1): 8 lanes/node x uint4(16B), 4-deep.
// ---------------------------------------------------------------------------
__global__ __launch_bounds__(256) void gather_sum8(
    const unsigned short* __restrict__ h16, const unsigned* __restrict__ slots,
    const int* __restrict__ offs, float* __restrict__ agg, int N)
{
    const int g = blockIdx.x * 256 + threadIdx.x;
    const int n = g >> 3;
    if (n >= N) return;
    const int c = (g & 7) * 8;
    const int beg = offs[n], end = offs[n + 1];
    float a[8] = {0.f, 0.f, 0.f, 0.f, 0.f, 0.f, 0.f, 0.f};
    int j = beg;
    for (; j + 4 <= end; j += 4) {
        const unsigned s0 = slots[j],     s1 = slots[j + 1];
        const unsigned s2 = slots[j + 2], s3 = slots[j + 3];
        const uint4 u0 = *(const uint4*)(h16 + (size_t)s0 * 64 + c);
        const uint4 u1 = *(const uint4*)(h16 + (size_t)s1 * 64 + c);
        const uint4 u2 = *(const uint4*)(h16 + (size_t)s2 * 64 + c);
        const uint4 u3 = *(const uint4*)(h16 + (size_t)s3 * 64 + c);
        acc8(a, u0); acc8(a, u1); acc8(a, u2); acc8(a, u3);
    }
    for (; j < end; ++j) {
        const uint4 u0 = *(const uint4*)(h16 + (size_t)slots[j] * 64 + c);
        acc8(a, u0);
    }
    *(float4*)(agg + (size_t)n * 64 + c)     = make_float4(a[0], a[1], a[2], a[3]);
    *(float4*)(agg + (size_t)n * 64 + c + 4) = make_float4(a[4], a[5], a[6], a[7]);
}

extern "C" void kernel_launch(void* const* d_in, const int* in_sizes, int n_in,
                              void* d_out, int out_size, void* d_ws, size_t ws_size,
                              hipStream_t stream)
{
    const float* x       = (const float*)d_in[0];
    const int*   ei      = (const int*)  d_in[1];
    const float* W_pre   = (const float*)d_in[2];
    const float* b_pre   = (const float*)d_in[3];
    const float* W_first = (const float*)d_in[4];
    const float* b_first = (const float*)d_in[5];
    const float* W_out   = (const float*)d_in[6];
    const float* b_out   = (const float*)d_in[7];

    const int N = in_sizes[0] / 128;
    const int E = in_sizes[1] / 2;
    const int* src = ei;
    const int* dst = ei + E;

    const int NBK = (N >> 8) + 1;
    const int NC  = (E + CHUNK - 1) / CHUNK;
    const int nscan = NBK * NC;
    const int nsblk = (nscan + 255) / 256;        // <= 1024

    // Workspace layout (~46 MB):
    float*          h      = (float*)d_ws;                          // [N,64] f32
    unsigned short* h16    = (unsigned short*)(h + (size_t)N * 64); // [N,64] bf16
    unsigned*       slots  = (unsigned*)(h16 + (size_t)N * 64);     // [E]
    int*            counts = (int*)(slots + E);                     // [nscan]
    int*            partial= counts + nscan;                        // [<=1024]
    int*            offs   = partial + 1024;                        // [N+1]

    float* agg = (float*)d_out;   // agg for conv1; conv2 overwrites with out
    float* out = (float*)d_out;

    const int gemm_blocks   = (N + 63) / 64;      // 1563
    const int gather_blocks = (N * 8 + 255) / 256;

    // --- CSR build (d_out free as overflow scratch here) ---
    p_hist<<<NC, 256, 0, stream>>>(dst, counts, E, NBK, NC);
    k_blocksum<<<nsblk, 256, 0, stream>>>(counts, partial, nscan);
    k_scanpartial1024<<<1, 1024, 0, stream>>>(partial, nsblk);
    k_exscan<<<nsblk, 256, 0, stream>>>(counts, partial, nscan);
    p_scatter<<<NC, 256, 0, stream>>>(src, dst, counts, slots, E, NBK, NC);
    p_bucket<<<NBK, 256, 0, stream>>>(slots, counts, offs, (unsigned*)d_out,
                                      E, N, NBK, NC);

    // --- 1. h = x @ W_pre.T + b_pre  (+ bf16 mirror) ---
    gemm_mfma<128, 0, 1><<<gemm_blocks, 256, 0, stream>>>(
        x, nullptr, W_pre, b_pre, h, h16, N);

    // --- 2. conv1: agg = seg_sum(h16); h = relu((h+agg)@W_first.T + b) ---
    gather_sum8<<<gather_blocks, 256, 0, stream>>>(h16, slots, offs, agg, N);
    gemm_mfma<64, 1, 1><<<gemm_blocks, 256, 0, stream>>>(
        h, agg, W_first, b_first, h, h16, N);

    // --- 3. conv2 fused: out = (h + seg_sum(h16))@W_out.T + b_out ---
    conv2_fused<<<gemm_blocks, 256, 0, stream>>>(
        h, h16, slots, offs, W_out, b_out, out, N);
}

// Round 9
// 144.765 us; speedup vs baseline: 22.1874x; 1.1549x over previous
//
#include <hip/hip_runtime.h>

// GIN forward, all inter-stage tensors bf16 (MFMA quantizes at staging anyway):
//   h16a = bf16(x @ W_pre.T + b_pre)
//   h16b = bf16(relu((h16a + seg_sum(h16a[src])) @ W_first.T + b_first))
//   out  = (h16b + seg_sum(h16b[src])) @ W_out.T + b_out   (f32)
// N=100000, E=1600000. R9: f32 h path dropped, conv1 fused like conv2,
// p_hist merged into the pre-GEMM launch, 8-deep gather pipeline.

using bf16x8 = __attribute__((ext_vector_type(8))) short;
using f32x4  = __attribute__((ext_vector_type(4))) float;

__device__ inline unsigned short f2bf(float f) {
    unsigned b = __float_as_uint(f);
    return (unsigned short)((b + 0x7FFF + ((b >> 16) & 1)) >> 16);
}
__device__ inline float bf2f_lo(unsigned u) { return __uint_as_float(u << 16); }
__device__ inline float bf2f_hi(unsigned u) { return __uint_as_float(u & 0xFFFF0000u); }
__device__ inline unsigned packbf(float lo, float hi) {
    return (unsigned)f2bf(lo) | ((unsigned)f2bf(hi) << 16);
}
__device__ inline void acc8(float* a, const uint4 u) {
    a[0] += bf2f_lo(u.x); a[1] += bf2f_hi(u.x);
    a[2] += bf2f_lo(u.y); a[3] += bf2f_hi(u.y);
    a[4] += bf2f_lo(u.z); a[5] += bf2f_hi(u.z);
    a[6] += bf2f_lo(u.w); a[7] += bf2f_hi(u.w);
}

constexpr int CHUNK = 8192;

// ---------------------------------------------------------------------------
// K1: blocks [0,GB) = pre-GEMM h16a = bf16(x@W_pre.T + b_pre), K=128;
//     blocks [GB,GB+NC) = dst bucket histogram (independent work, overlapped).
// SP=136 ushorts = 272B row stride: 16B-aligned, 68 dwords = 4 mod 32 banks
// -> 2-way on MFMA frag reads (free).
// ---------------------------------------------------------------------------
__global__ __launch_bounds__(256) void k1_pre_hist(
    const float* __restrict__ x, const float* __restrict__ Wp,
    const float* __restrict__ bp, unsigned short* __restrict__ h16a, int N,
    const int* __restrict__ dst, int* __restrict__ counts,
    int E, int NBK, int NC, int GB)
{
    __shared__ char lds_raw[34816];
    const int tid = threadIdx.x;

    if (blockIdx.x >= GB) {                        // ---- histogram role ----
        int* cnt = (int*)lds_raw;
        const int c = blockIdx.x - GB;
        for (int b = tid; b < NBK; b += 256) cnt[b] = 0;
        __syncthreads();
        const int beg = c * CHUNK, end = min(beg + CHUNK, E);
        for (int e = beg + tid; e < end; e += 256)
            atomicAdd(&cnt[dst[e] >> 8], 1);
        __syncthreads();
        for (int b = tid; b < NBK; b += 256) counts[b * NC + c] = cnt[b];
        return;
    }

    // ---- GEMM role ----
    constexpr int SP = 136;
    unsigned short (*xs)[SP] = (unsigned short(*)[SP])lds_raw;
    unsigned short (*ws)[SP] = (unsigned short(*)[SP])(lds_raw + 64 * SP * 2);
    const int base = blockIdx.x * 64;

    for (int i = tid; i < 64 * 32; i += 256) {     // stage W_pre -> bf16
        const int r = i >> 5, q = i & 31;
        const float4 v = *(const float4*)(Wp + r * 128 + q * 4);
        *(ushort4*)&ws[r][q * 4] =
            make_ushort4(f2bf(v.x), f2bf(v.y), f2bf(v.z), f2bf(v.w));
    }
    for (int i = tid; i < 64 * 32; i += 256) {     // stage x -> bf16
        const int r = i >> 5, q = i & 31;
        int row = base + r; if (row > N - 1) row = N - 1;
        const float4 v = *(const float4*)(x + (size_t)row * 128 + q * 4);
        *(ushort4*)&xs[r][q * 4] =
            make_ushort4(f2bf(v.x), f2bf(v.y), f2bf(v.z), f2bf(v.w));
    }
    __syncthreads();

    const int w = tid >> 6, l = tid & 63, lr = l & 15, lg = l >> 4;
    f32x4 acc[4];
#pragma unroll
    for (int nb = 0; nb < 4; ++nb) {
        const float bv = bp[nb * 16 + lr];
        acc[nb] = (f32x4){bv, bv, bv, bv};
    }
#pragma unroll
    for (int kb = 0; kb < 4; ++kb) {
        const bf16x8 a = *(const bf16x8*)&xs[w * 16 + lr][kb * 32 + lg * 8];
#pragma unroll
        for (int nb = 0; nb < 4; ++nb) {
            const bf16x8 b = *(const bf16x8*)&ws[nb * 16 + lr][kb * 32 + lg * 8];
            acc[nb] = __builtin_amdgcn_mfma_f32_16x16x32_bf16(a, b, acc[nb], 0, 0, 0);
        }
    }
#pragma unroll
    for (int nb = 0; nb < 4; ++nb) {
#pragma unroll
        for (int r = 0; r < 4; ++r) {
            const int row = base + w * 16 + lg * 4 + r;
            if (row < N)
                h16a[(size_t)row * 64 + nb * 16 + lr] = f2bf(acc[nb][r]);
        }
    }
}

// ---------------------------------------------------------------------------
// Fused GIN conv: res = act((hin[node] + seg_sum(hin[slots])) @ W.T + bias).
// Gather: 8 lanes/node x 16B, 8-deep load pipeline. MFMA: K=64, 64x64 tile.
// WF32=1 -> write f32 outf (d_out); WF32=0 -> write bf16 out16 (next stage).
// ---------------------------------------------------------------------------
template <int RELU, int WF32>
__global__ __launch_bounds__(256) void conv_fused(
    const unsigned short* __restrict__ hin, const unsigned* __restrict__ slots,
    const int* __restrict__ offs, const float* __restrict__ W,
    const float* __restrict__ bias, float* __restrict__ outf,
    unsigned short* __restrict__ out16, int N)
{
    constexpr int SP = 72;   // 144B stride: 16B-aligned, 36 dwords = 4 mod 32
    __shared__ unsigned short xs[64][SP];
    __shared__ unsigned short ws[64][SP];
    const int tid = threadIdx.x;
    const int base = blockIdx.x * 64;

    for (int i = tid; i < 64 * 16; i += 256) {     // stage W -> bf16
        const int r = i >> 4, q = i & 15;
        const float4 v = *(const float4*)(W + r * 64 + q * 4);
        *(ushort4*)&ws[r][q * 4] =
            make_ushort4(f2bf(v.x), f2bf(v.y), f2bf(v.z), f2bf(v.w));
    }

    const int nloc = tid >> 3;                     // 0..31
    const int c    = (tid & 7) * 8;                // col offset (elems)
#pragma unroll
    for (int p = 0; p < 2; ++p) {
        const int node = base + p * 32 + nloc;
        float a[8] = {0.f, 0.f, 0.f, 0.f, 0.f, 0.f, 0.f, 0.f};
        if (node < N) {
            acc8(a, *(const uint4*)(hin + (size_t)node * 64 + c));  // self term
            const int beg = offs[node], end = offs[node + 1];
            int j = beg;
            for (; j + 8 <= end; j += 8) {         // 8 rows in flight
                const unsigned s0 = slots[j],     s1 = slots[j + 1];
                const unsigned s2 = slots[j + 2], s3 = slots[j + 3];
                const unsigned s4 = slots[j + 4], s5 = slots[j + 5];
                const unsigned s6 = slots[j + 6], s7 = slots[j + 7];
                const uint4 u0 = *(const uint4*)(hin + (size_t)s0 * 64 + c);
                const uint4 u1 = *(const uint4*)(hin + (size_t)s1 * 64 + c);
                const uint4 u2 = *(const uint4*)(hin + (size_t)s2 * 64 + c);
                const uint4 u3 = *(const uint4*)(hin + (size_t)s3 * 64 + c);
                const uint4 u4 = *(const uint4*)(hin + (size_t)s4 * 64 + c);
                const uint4 u5 = *(const uint4*)(hin + (size_t)s5 * 64 + c);
                const uint4 u6 = *(const uint4*)(hin + (size_t)s6 * 64 + c);
                const uint4 u7 = *(const uint4*)(hin + (size_t)s7 * 64 + c);
                acc8(a, u0); acc8(a, u1); acc8(a, u2); acc8(a, u3);
                acc8(a, u4); acc8(a, u5); acc8(a, u6); acc8(a, u7);
            }
            for (; j + 4 <= end; j += 4) {
                const unsigned s0 = slots[j],     s1 = slots[j + 1];
                const unsigned s2 = slots[j + 2], s3 = slots[j + 3];
                const uint4 u0 = *(const uint4*)(hin + (size_t)s0 * 64 + c);
                const uint4 u1 = *(const uint4*)(hin + (size_t)s1 * 64 + c);
                const uint4 u2 = *(const uint4*)(hin + (size_t)s2 * 64 + c);
                const uint4 u3 = *(const uint4*)(hin + (size_t)s3 * 64 + c);
                acc8(a, u0); acc8(a, u1); acc8(a, u2); acc8(a, u3);
            }
            for (; j < end; ++j)
                acc8(a, *(const uint4*)(hin + (size_t)slots[j] * 64 + c));
        }
        *(uint4*)&xs[p * 32 + nloc][c] =
            make_uint4(packbf(a[0], a[1]), packbf(a[2], a[3]),
                       packbf(a[4], a[5]), packbf(a[6], a[7]));
    }
    __syncthreads();

    const int w = tid >> 6, l = tid & 63, lr = l & 15, lg = l >> 4;
    f32x4 acc[4];
#pragma unroll
    for (int nb = 0; nb < 4; ++nb) {
        const float bv = bias[nb * 16 + lr];
        acc[nb] = (f32x4){bv, bv, bv, bv};
    }
#pragma unroll
    for (int kb = 0; kb < 2; ++kb) {
        const bf16x8 a = *(const bf16x8*)&xs[w * 16 + lr][kb * 32 + lg * 8];
#pragma unroll
        for (int nb = 0; nb < 4; ++nb) {
            const bf16x8 b = *(const bf16x8*)&ws[nb * 16 + lr][kb * 32 + lg * 8];
            acc[nb] = __builtin_amdgcn_mfma_f32_16x16x32_bf16(a, b, acc[nb], 0, 0, 0);
        }
    }
#pragma unroll
    for (int nb = 0; nb < 4; ++nb) {
#pragma unroll
        for (int r = 0; r < 4; ++r) {
            const int row = base + w * 16 + lg * 4 + r;
            if (row < N) {
                float v = acc[nb][r];
                if (RELU) v = fmaxf(v, 0.f);
                if (WF32) outf[(size_t)row * 64 + nb * 16 + lr] = v;
                else      out16[(size_t)row * 64 + nb * 16 + lr] = f2bf(v);
            }
        }
    }
}

// ---------------------------------------------------------------------------
// CSR scan chain + scatter + per-bucket sort (R5/R8 structure).
// ---------------------------------------------------------------------------
__global__ __launch_bounds__(256) void k_blocksum(
    const int* __restrict__ in, int* __restrict__ partial, int n)
{
    __shared__ int s[256];
    const int i = blockIdx.x * 256 + threadIdx.x;
    s[threadIdx.x] = (i < n) ? in[i] : 0;
    __syncthreads();
    for (int off = 128; off > 0; off >>= 1) {
        if (threadIdx.x < off) s[threadIdx.x] += s[threadIdx.x + off];
        __syncthreads();
    }
    if (threadIdx.x == 0) partial[blockIdx.x] = s[0];
}

__global__ __launch_bounds__(1024) void k_scanpartial1024(
    int* __restrict__ partial, int nblk)
{
    __shared__ int s[1024];
    const int t = threadIdx.x;
    s[t] = (t < nblk) ? partial[t] : 0;
    __syncthreads();
    for (int off = 1; off < 1024; off <<= 1) {
        const int v = (t >= off) ? s[t - off] : 0;
        __syncthreads();
        s[t] += v;
        __syncthreads();
    }
    if (t < nblk) partial[t] = (t == 0) ? 0 : s[t - 1];
}

__global__ __launch_bounds__(256) void k_exscan(
    int* __restrict__ data, const int* __restrict__ partial, int n)
{
    __shared__ int s[256];
    const int i = blockIdx.x * 256 + threadIdx.x;
    const int t = threadIdx.x;
    const int v = (i < n) ? data[i] : 0;
    s[t] = v;
    __syncthreads();
    for (int off = 1; off < 256; off <<= 1) {
        const int u = (t >= off) ? s[t - off] : 0;
        __syncthreads();
        s[t] += u;
        __syncthreads();
    }
    if (i < n) data[i] = partial[blockIdx.x] + s[t] - v;   // exclusive
}

__global__ __launch_bounds__(256) void p_scatter(
    const int* __restrict__ src, const int* __restrict__ dst,
    const int* __restrict__ counts, unsigned* __restrict__ slots,
    int E, int NBK, int NC)
{
    __shared__ int cur[512];
    const int c = blockIdx.x;
    for (int b = threadIdx.x; b < NBK; b += 256) cur[b] = counts[b * NC + c];
    __syncthreads();
    const int beg = c * CHUNK;
    const int end = min(beg + CHUNK, E);
    for (int e = beg + threadIdx.x; e < end; e += 256) {
        const int d = dst[e];
        const int pos = atomicAdd(&cur[d >> 8], 1);
        slots[pos] = ((unsigned)(d & 255) << 24) | (unsigned)src[e];
    }
}

__global__ __launch_bounds__(256) void p_bucket(
    unsigned* __restrict__ slots, const int* __restrict__ counts,
    int* __restrict__ offs, unsigned* __restrict__ scratch,
    int E, int N, int NBK, int NC)
{
    __shared__ int cnt[256];
    __shared__ int noff[256];
    __shared__ unsigned outl[8192];
    const int b = blockIdx.x;
    const int t = threadIdx.x;
    const int base = counts[b * NC];
    const int next = (b == NBK - 1) ? E : counts[(b + 1) * NC];
    const int size = next - base;

    cnt[t] = 0;
    __syncthreads();
    for (int i = t; i < size; i += 256)
        atomicAdd(&cnt[slots[base + i] >> 24], 1);
    __syncthreads();

    const int v = cnt[t];
    noff[t] = v;
    __syncthreads();
    for (int off = 1; off < 256; off <<= 1) {
        const int u = (t >= off) ? noff[t - off] : 0;
        __syncthreads();
        noff[t] += u;
        __syncthreads();
    }
    const int ex = noff[t] - v;
    __syncthreads();
    noff[t] = ex;
    cnt[t] = ex;
    __syncthreads();

    const int node = (b << 8) + t;
    if (node <= N) offs[node] = base + noff[t];

    if (size <= 8192) {
        for (int i = t; i < size; i += 256) {
            const unsigned p = slots[base + i];
            const int pos = atomicAdd(&cnt[p >> 24], 1);
            outl[pos] = p & 0x00FFFFFFu;
        }
        __syncthreads();
        for (int i = t; i < size; i += 256) slots[base + i] = outl[i];
    } else {
        for (int i = t; i < size; i += 256) scratch[base + i] = slots[base + i];
        __threadfence();
        __syncthreads();
        for (int i = t; i < size; i += 256) {
            const unsigned p = scratch[base + i];
            const int pos = atomicAdd(&cnt[p >> 24], 1);
            slots[base + pos] = p & 0x00FFFFFFu;
        }
    }
}

extern "C" void kernel_launch(void* const* d_in, const int* in_sizes, int n_in,
                              void* d_out, int out_size, void* d_ws, size_t ws_size,
                              hipStream_t stream)
{
    const float* x       = (const float*)d_in[0];
    const int*   ei      = (const int*)  d_in[1];
    const float* W_pre   = (const float*)d_in[2];
    const float* b_pre   = (const float*)d_in[3];
    const float* W_first = (const float*)d_in[4];
    const float* b_first = (const float*)d_in[5];
    const float* W_out   = (const float*)d_in[6];
    const float* b_out   = (const float*)d_in[7];

    const int N = in_sizes[0] / 128;
    const int E = in_sizes[1] / 2;
    const int* src = ei;
    const int* dst = ei + E;

    const int NBK = (N >> 8) + 1;
    const int NC  = (E + CHUNK - 1) / CHUNK;
    const int nscan = NBK * NC;
    const int nsblk = (nscan + 255) / 256;        // <= 1024

    // Workspace (~33 MB): h16a/h16b bf16 states, slots, scan arrays.
    unsigned short* h16a   = (unsigned short*)d_ws;              // [N*64]
    unsigned short* h16b   = h16a + (size_t)N * 64;              // [N*64]
    unsigned*       slots  = (unsigned*)(h16b + (size_t)N * 64); // [E]
    int*            counts = (int*)(slots + E);                  // [nscan]
    int*            partial= counts + nscan;                     // [<=1024]
    int*            offs   = partial + 1024;                     // [N+1]

    float* out = (float*)d_out;

    const int GB = (N + 63) / 64;                 // 1563 GEMM/conv blocks

    // K1: pre-GEMM || dst histogram
    k1_pre_hist<<<GB + NC, 256, 0, stream>>>(
        x, W_pre, b_pre, h16a, N, dst, counts, E, NBK, NC, GB);

    // CSR scan chain
    k_blocksum<<<nsblk, 256, 0, stream>>>(counts, partial, nscan);
    k_scanpartial1024<<<1, 1024, 0, stream>>>(partial, nsblk);
    k_exscan<<<nsblk, 256, 0, stream>>>(counts, partial, nscan);
    p_scatter<<<NC, 256, 0, stream>>>(src, dst, counts, slots, E, NBK, NC);
    p_bucket<<<NBK, 256, 0, stream>>>(slots, counts, offs, (unsigned*)d_out,
                                      E, N, NBK, NC);

    // conv1 fused -> h16b (bf16), relu
    conv_fused<1, 0><<<GB, 256, 0, stream>>>(
        h16a, slots, offs, W_first, b_first, nullptr, h16b, N);

    // conv2 fused -> d_out (f32)
    conv_fused<0, 1><<<GB, 256, 0, stream>>>(
        h16b, slots, offs, W_out, b_out, out, nullptr, N);
}